// Round 9
// baseline (763.094 us; speedup 1.0000x reference)
//
#include <hip/hip_runtime.h>

#define N_COL 100000
#define N_CON 20000
#define HDIM 128
#define SCAN_B 1024  // elements scanned per block (256 thr x 4)

// ---------- tiny transpose: dst[c*R+r] = src[r*C+c] ----------
__global__ void transpose_k(const float* __restrict__ src, float* __restrict__ dst, int R, int C) {
    int idx = blockIdx.x * blockDim.x + threadIdx.x;
    if (idx < R * C) {
        int r = idx / C, c = idx - r * C;
        dst[c * R + r] = src[idx];
    }
}

// ---------- encoder: out[n,h] = relu(sum_k x[n,k]*WT[k,h] + b[h]) ----------
template <int D>
__global__ __launch_bounds__(256) void encoder_k(const float* __restrict__ x,
                                                 const float* __restrict__ WT,
                                                 const float* __restrict__ b,
                                                 float* __restrict__ out, int N) {
    int idx = blockIdx.x * blockDim.x + threadIdx.x;
    if (idx >= N * HDIM) return;
    int n = idx >> 7, h = idx & 127;
    const float* xr = x + (size_t)n * D;
    float acc = b[h];
#pragma unroll
    for (int k = 0; k < D; k++) acc = fmaf(xr[k], WT[k * HDIM + h], acc);
    out[idx] = fmaxf(acc, 0.f);
}

// ---------- CSR build ----------
__global__ void count_k(const int* __restrict__ ecol, const int* __restrict__ econ,
                        int* cnt_col, int* cnt_con, int E) {
    int e = blockIdx.x * blockDim.x + threadIdx.x;
    if (e < E) {
        atomicAdd(&cnt_col[ecol[e]], 1);
        atomicAdd(&cnt_con[econ[e]], 1);
    }
}

__global__ __launch_bounds__(256) void scan1_k(const int* __restrict__ cnt, int n,
                                               int* __restrict__ offs, int* __restrict__ partials) {
    __shared__ int lds[256];
    int t = threadIdx.x;
    int base = blockIdx.x * SCAN_B + t * 4;
    int v[4], s = 0;
#pragma unroll
    for (int i = 0; i < 4; i++) { int idx = base + i; v[i] = (idx < n) ? cnt[idx] : 0; s += v[i]; }
    lds[t] = s; __syncthreads();
    for (int off = 1; off < 256; off <<= 1) {
        int x = (t >= off) ? lds[t - off] : 0; __syncthreads();
        lds[t] += x; __syncthreads();
    }
    int excl = lds[t] - s;
    if (t == 255) partials[blockIdx.x] = lds[255];
    int run = excl;
#pragma unroll
    for (int i = 0; i < 4; i++) { int idx = base + i; if (idx < n) offs[idx] = run; run += v[i]; }
}

__global__ __launch_bounds__(256) void scan2_k(int* partials, int nb) {
    __shared__ int lds[256];
    int t = threadIdx.x;
    int v = (t < nb) ? partials[t] : 0;
    lds[t] = v; __syncthreads();
    for (int off = 1; off < 256; off <<= 1) {
        int x = (t >= off) ? lds[t - off] : 0; __syncthreads();
        lds[t] += x; __syncthreads();
    }
    if (t < nb) partials[t] = lds[t] - v;
}

__global__ void scan3_k(int* offs, int n, const int* __restrict__ partials) {
    int i = blockIdx.x * blockDim.x + threadIdx.x;
    if (i < n) offs[i] += partials[i / SCAN_B];
}

__global__ void fill_k(const int* __restrict__ sidx, const int* __restrict__ didx,
                       const int* __restrict__ offs, int* cursor, int* __restrict__ srclist, int E) {
    int e = blockIdx.x * blockDim.x + threadIdx.x;
    if (e < E) {
        int d = didx[e];
        int p = offs[d] + atomicAdd(&cursor[d], 1);
        srclist[p] = sidx[e];
    }
}

// ---------- gather segment-mean: one wave per dst node ----------
__global__ __launch_bounds__(256) void gather_mean_k(const float* __restrict__ tab,
                                                     const int* __restrict__ srclist,
                                                     const int* __restrict__ offs,
                                                     const int* __restrict__ cnt,
                                                     float* __restrict__ out, int N) {
    int wid = threadIdx.x >> 6, lane = threadIdx.x & 63;
    int n = blockIdx.x * 4 + wid;
    if (n >= N) return;
    int c = cnt[n], st = offs[n];
    const int* sl = srclist + st;
    int half = lane >> 5, q = (lane & 31) * 4;
    float ax = 0.f, ay = 0.f, az = 0.f, aw = 0.f;
    int j = 0;
    for (; j + 1 < c; j += 2) {
        int s = sl[j + half];
        float4 a = *reinterpret_cast<const float4*>(tab + (size_t)s * HDIM + q);
        ax += a.x; ay += a.y; az += a.z; aw += a.w;
    }
    if (j < c && half == 0) {
        int s = sl[j];
        float4 a = *reinterpret_cast<const float4*>(tab + (size_t)s * HDIM + q);
        ax += a.x; ay += a.y; az += a.z; aw += a.w;
    }
    ax += __shfl_xor(ax, 32); ay += __shfl_xor(ay, 32);
    az += __shfl_xor(az, 32); aw += __shfl_xor(aw, 32);
    if (half == 0) {
        float inv = 1.f / fmaxf((float)c, 1.f);
        float4 r; r.x = ax * inv; r.y = ay * inv; r.z = az * inv; r.w = aw * inv;
        *reinterpret_cast<float4*>(out + (size_t)n * HDIM + q) = r;
    }
}

// ======== GEMM core: one K=128 pass, global A staged via As, float4 A reads ========
// thread = 4 rows (ty*4..+3) x 8 cols (tx*4..+3, 64+tx*4..+3)
__device__ __forceinline__ void gemm_core(float (*As)[36], float (*Ws)[132],
                                          const float* __restrict__ src,
                                          const float* __restrict__ W,
                                          int n0, int N, int t, float acc[4][8]) {
    int tx = t & 15, ty = t >> 4;
    int ar = t >> 2, akq = (t & 3) * 8;
    int wk = t >> 3, wc = (t & 7) * 16;
    for (int kb = 0; kb < 4; ++kb) {
        int k0 = kb * 32;
        {
            int row = n0 + ar;
            float4 v0 = make_float4(0.f, 0.f, 0.f, 0.f), v1 = v0;
            if (row < N) {
                const float* ap = src + (size_t)row * HDIM + k0 + akq;
                v0 = *reinterpret_cast<const float4*>(ap);
                v1 = *reinterpret_cast<const float4*>(ap + 4);
            }
            *reinterpret_cast<float4*>(&As[ar][akq]) = v0;
            *reinterpret_cast<float4*>(&As[ar][akq + 4]) = v1;
        }
        {
            const float* wp = W + (size_t)(k0 + wk) * HDIM + wc;
#pragma unroll
            for (int jj = 0; jj < 4; jj++)
                *reinterpret_cast<float4*>(&Ws[wk][wc + 4 * jj]) =
                    *reinterpret_cast<const float4*>(wp + 4 * jj);
        }
        __syncthreads();
#pragma unroll
        for (int k4 = 0; k4 < 8; ++k4) {
            float4 av[4];
#pragma unroll
            for (int i = 0; i < 4; i++)
                av[i] = *reinterpret_cast<const float4*>(&As[ty * 4 + i][k4 * 4]);
#pragma unroll
            for (int kk = 0; kk < 4; kk++) {
                float4 w0 = *reinterpret_cast<const float4*>(&Ws[k4 * 4 + kk][tx * 4]);
                float4 w1 = *reinterpret_cast<const float4*>(&Ws[k4 * 4 + kk][64 + tx * 4]);
                float w[8] = {w0.x, w0.y, w0.z, w0.w, w1.x, w1.y, w1.z, w1.w};
#pragma unroll
                for (int i = 0; i < 4; i++) {
                    float avk = (kk == 0) ? av[i].x : (kk == 1) ? av[i].y
                                : (kk == 2) ? av[i].z : av[i].w;
#pragma unroll
                    for (int j = 0; j < 8; j++) acc[i][j] = fmaf(avk, w[j], acc[i][j]);
                }
            }
        }
        __syncthreads();
    }
}

// ======== GEMM core with A already resident in LDS (H[64][132]) — no A staging, no global A ========
__device__ __forceinline__ void gemm_core_h(float (*Ha)[132], float (*Ws)[132],
                                            const float* __restrict__ W,
                                            int t, float acc[4][8]) {
    int tx = t & 15, ty = t >> 4;
    int wk = t >> 3, wc = (t & 7) * 16;
    for (int kb = 0; kb < 4; ++kb) {
        int k0 = kb * 32;
        {
            const float* wp = W + (size_t)(k0 + wk) * HDIM + wc;
#pragma unroll
            for (int jj = 0; jj < 4; jj++)
                *reinterpret_cast<float4*>(&Ws[wk][wc + 4 * jj]) =
                    *reinterpret_cast<const float4*>(wp + 4 * jj);
        }
        __syncthreads();
#pragma unroll
        for (int k4 = 0; k4 < 8; ++k4) {
            float4 av[4];
#pragma unroll
            for (int i = 0; i < 4; i++)
                av[i] = *reinterpret_cast<const float4*>(&Ha[ty * 4 + i][k0 + k4 * 4]);
#pragma unroll
            for (int kk = 0; kk < 4; kk++) {
                float4 w0 = *reinterpret_cast<const float4*>(&Ws[k4 * 4 + kk][tx * 4]);
                float4 w1 = *reinterpret_cast<const float4*>(&Ws[k4 * 4 + kk][64 + tx * 4]);
                float w[8] = {w0.x, w0.y, w0.z, w0.w, w1.x, w1.y, w1.z, w1.w};
#pragma unroll
                for (int i = 0; i < 4; i++) {
                    float avk = (kk == 0) ? av[i].x : (kk == 1) ? av[i].y
                                : (kk == 2) ? av[i].z : av[i].w;
#pragma unroll
                    for (int j = 0; j < 8; j++) acc[i][j] = fmaf(avk, w[j], acc[i][j]);
                }
            }
        }
        __syncthreads();
    }
}

// ---------- lin_k: out = src @ WT (no bias/relu) ----------
__global__ __launch_bounds__(256) void lin_k(const float* __restrict__ src,
                                             const float* __restrict__ WT,
                                             float* __restrict__ out, int N) {
    __shared__ __align__(16) float As[64][36];
    __shared__ __align__(16) float Ws[32][132];
    int t = threadIdx.x;
    int tx = t & 15, ty = t >> 4;
    int n0 = blockIdx.x * 64;
    float acc[4][8];
#pragma unroll
    for (int i = 0; i < 4; i++)
#pragma unroll
        for (int j = 0; j < 8; j++) acc[i][j] = 0.f;
    gemm_core(As, Ws, src, WT, n0, N, t, acc);
#pragma unroll
    for (int i = 0; i < 4; i++) {
        int row = n0 + ty * 4 + i;
        if (row < N) {
            float* op = out + (size_t)row * HDIM;
            *reinterpret_cast<float4*>(op + tx * 4) = make_float4(acc[i][0], acc[i][1], acc[i][2], acc[i][3]);
            *reinterpret_cast<float4*>(op + 64 + tx * 4) = make_float4(acc[i][4], acc[i][5], acc[i][6], acc[i][7]);
        }
    }
}

// ---------- dual-GEMM SAGE post (dst=con): out = relu(agg@WlT + x@WrT + bl) ----------
__global__ __launch_bounds__(256) void sage_gemm_k(const float* __restrict__ agg,
                                                   const float* __restrict__ xdst,
                                                   const float* __restrict__ WlT,
                                                   const float* __restrict__ bl,
                                                   const float* __restrict__ WrT,
                                                   float* __restrict__ out, int N) {
    __shared__ __align__(16) float As[64][36];
    __shared__ __align__(16) float Ws[32][132];
    int t = threadIdx.x;
    int tx = t & 15, ty = t >> 4;
    int n0 = blockIdx.x * 64;
    float acc[4][8];
#pragma unroll
    for (int i = 0; i < 4; i++)
#pragma unroll
        for (int j = 0; j < 8; j++) acc[i][j] = 0.f;
    gemm_core(As, Ws, agg, WlT, n0, N, t, acc);
    gemm_core(As, Ws, xdst, WrT, n0, N, t, acc);
    float4 b0 = *reinterpret_cast<const float4*>(bl + tx * 4);
    float4 b1 = *reinterpret_cast<const float4*>(bl + 64 + tx * 4);
    float bb[8] = {b0.x, b0.y, b0.z, b0.w, b1.x, b1.y, b1.z, b1.w};
#pragma unroll
    for (int i = 0; i < 4; i++) {
        int row = n0 + ty * 4 + i;
        if (row < N) {
            float4 r0, r1;
            r0.x = fmaxf(acc[i][0] + bb[0], 0.f);
            r0.y = fmaxf(acc[i][1] + bb[1], 0.f);
            r0.z = fmaxf(acc[i][2] + bb[2], 0.f);
            r0.w = fmaxf(acc[i][3] + bb[3], 0.f);
            r1.x = fmaxf(acc[i][4] + bb[4], 0.f);
            r1.y = fmaxf(acc[i][5] + bb[5], 0.f);
            r1.z = fmaxf(acc[i][6] + bb[6], 0.f);
            r1.w = fmaxf(acc[i][7] + bb[7], 0.f);
            float* op = out + (size_t)row * HDIM;
            *reinterpret_cast<float4*>(op + tx * 4) = r0;
            *reinterpret_cast<float4*>(op + 64 + tx * 4) = r1;
        }
    }
}

// ---------- col mega-kernel: conv1-nc + conv2-nc + Q-head, n_col never leaves LDS ----------
// H = relu(c0_1 + h_col@Wr1T + bl1)   (GEMM1, A staged from global)
// H2 = relu(c0_2 + H@Wr2T + bl2)      (GEMM2, A read from LDS H directly)
// out = relu(H2@W1T + b1)@W2 + b2
__global__ __launch_bounds__(256) void col_mega_k(const float* __restrict__ c0_1,
                                                  const float* __restrict__ c0_2,
                                                  const float* __restrict__ xdst,
                                                  const float* __restrict__ Wr1T,
                                                  const float* __restrict__ bl1,
                                                  const float* __restrict__ Wr2T,
                                                  const float* __restrict__ bl2,
                                                  const float* __restrict__ W1T,
                                                  const float* __restrict__ b1v,
                                                  const float* __restrict__ W2,
                                                  const float* __restrict__ b2,
                                                  float* __restrict__ out, int N) {
    __shared__ __align__(16) char smem[59904];  // H 33792 | As 9216 | Ws 16896
    float (*H)[132] = reinterpret_cast<float(*)[132]>(smem);
    float (*As)[36] = reinterpret_cast<float(*)[36]>(smem + 33792);
    float (*Ws)[132] = reinterpret_cast<float(*)[132]>(smem + 43008);
    int t = threadIdx.x;
    int tx = t & 15, ty = t >> 4;
    int n0 = blockIdx.x * 64;
    float acc[4][8];
#pragma unroll
    for (int i = 0; i < 4; i++)
#pragma unroll
        for (int j = 0; j < 8; j++) acc[i][j] = 0.f;

    // ---- GEMM1: n_col tile ----
    gemm_core(As, Ws, xdst, Wr1T, n0, N, t, acc);
    {
        float4 b0 = *reinterpret_cast<const float4*>(bl1 + tx * 4);
        float4 b1 = *reinterpret_cast<const float4*>(bl1 + 64 + tx * 4);
        float bb[8] = {b0.x, b0.y, b0.z, b0.w, b1.x, b1.y, b1.z, b1.w};
#pragma unroll
        for (int i = 0; i < 4; i++) {
            int row = n0 + ty * 4 + i;
            float4 ca = make_float4(0.f, 0.f, 0.f, 0.f), cb = ca;
            if (row < N) {
                const float* cp = c0_1 + (size_t)row * HDIM;
                ca = *reinterpret_cast<const float4*>(cp + tx * 4);
                cb = *reinterpret_cast<const float4*>(cp + 64 + tx * 4);
            }
            float* hp = &H[ty * 4 + i][0];
            *reinterpret_cast<float4*>(hp + tx * 4) = make_float4(
                fmaxf(acc[i][0] + ca.x + bb[0], 0.f), fmaxf(acc[i][1] + ca.y + bb[1], 0.f),
                fmaxf(acc[i][2] + ca.z + bb[2], 0.f), fmaxf(acc[i][3] + ca.w + bb[3], 0.f));
            *reinterpret_cast<float4*>(hp + 64 + tx * 4) = make_float4(
                fmaxf(acc[i][4] + cb.x + bb[4], 0.f), fmaxf(acc[i][5] + cb.y + bb[5], 0.f),
                fmaxf(acc[i][6] + cb.z + bb[6], 0.f), fmaxf(acc[i][7] + cb.w + bb[7], 0.f));
        }
    }
    __syncthreads();

    // ---- GEMM2: h_col2 tile, A straight from LDS H ----
#pragma unroll
    for (int i = 0; i < 4; i++)
#pragma unroll
        for (int j = 0; j < 8; j++) acc[i][j] = 0.f;
    gemm_core_h(H, Ws, Wr2T, t, acc);
    // (core ends with barrier -> safe to overwrite H with H2)
    {
        float4 b0 = *reinterpret_cast<const float4*>(bl2 + tx * 4);
        float4 b1 = *reinterpret_cast<const float4*>(bl2 + 64 + tx * 4);
        float bb[8] = {b0.x, b0.y, b0.z, b0.w, b1.x, b1.y, b1.z, b1.w};
#pragma unroll
        for (int i = 0; i < 4; i++) {
            int row = n0 + ty * 4 + i;
            float4 ca = make_float4(0.f, 0.f, 0.f, 0.f), cb = ca;
            if (row < N) {
                const float* cp = c0_2 + (size_t)row * HDIM;
                ca = *reinterpret_cast<const float4*>(cp + tx * 4);
                cb = *reinterpret_cast<const float4*>(cp + 64 + tx * 4);
            }
            float* hp = &H[ty * 4 + i][0];
            *reinterpret_cast<float4*>(hp + tx * 4) = make_float4(
                fmaxf(acc[i][0] + ca.x + bb[0], 0.f), fmaxf(acc[i][1] + ca.y + bb[1], 0.f),
                fmaxf(acc[i][2] + ca.z + bb[2], 0.f), fmaxf(acc[i][3] + ca.w + bb[3], 0.f));
            *reinterpret_cast<float4*>(hp + 64 + tx * 4) = make_float4(
                fmaxf(acc[i][4] + cb.x + bb[4], 0.f), fmaxf(acc[i][5] + cb.y + bb[5], 0.f),
                fmaxf(acc[i][6] + cb.z + bb[6], 0.f), fmaxf(acc[i][7] + cb.w + bb[7], 0.f));
        }
    }
    __syncthreads();

    // ---- Q-head: y = relu(H@W1T + b1) [64x64]; q = y@W2 + b2 ----
    int tx2 = t & 7, ty2 = t >> 3;
    float acc2[2][8];
#pragma unroll
    for (int i = 0; i < 2; i++)
#pragma unroll
        for (int j = 0; j < 8; j++) acc2[i][j] = 0.f;
    for (int k4 = 0; k4 < HDIM / 4; ++k4) {
        float4 a0 = *reinterpret_cast<const float4*>(&H[ty2 * 2 + 0][k4 * 4]);
        float4 a1 = *reinterpret_cast<const float4*>(&H[ty2 * 2 + 1][k4 * 4]);
        float a[2][4] = {{a0.x, a0.y, a0.z, a0.w}, {a1.x, a1.y, a1.z, a1.w}};
#pragma unroll
        for (int kk = 0; kk < 4; kk++) {
            const float* wp = W1T + (size_t)(k4 * 4 + kk) * 64 + tx2 * 8;
            float4 w0 = *reinterpret_cast<const float4*>(wp);
            float4 w1 = *reinterpret_cast<const float4*>(wp + 4);
            float w[8] = {w0.x, w0.y, w0.z, w0.w, w1.x, w1.y, w1.z, w1.w};
#pragma unroll
            for (int i = 0; i < 2; i++)
#pragma unroll
                for (int j = 0; j < 8; j++) acc2[i][j] = fmaf(a[i][kk], w[j], acc2[i][j]);
        }
    }
    {
        float4 c0v = *reinterpret_cast<const float4*>(b1v + tx2 * 8);
        float4 c1v = *reinterpret_cast<const float4*>(b1v + tx2 * 8 + 4);
        float bb1[8] = {c0v.x, c0v.y, c0v.z, c0v.w, c1v.x, c1v.y, c1v.z, c1v.w};
        float4 d0 = *reinterpret_cast<const float4*>(W2 + tx2 * 8);
        float4 d1 = *reinterpret_cast<const float4*>(W2 + tx2 * 8 + 4);
        float w2[8] = {d0.x, d0.y, d0.z, d0.w, d1.x, d1.y, d1.z, d1.w};
#pragma unroll
        for (int i = 0; i < 2; i++) {
            float v = 0.f;
#pragma unroll
            for (int j = 0; j < 8; j++) v = fmaf(fmaxf(acc2[i][j] + bb1[j], 0.f), w2[j], v);
            v += __shfl_xor(v, 1);
            v += __shfl_xor(v, 2);
            v += __shfl_xor(v, 4);
            int row = n0 + ty2 * 2 + i;
            if (tx2 == 0 && row < N) out[row] = v + b2[0];
        }
    }
}

extern "C" void kernel_launch(void* const* d_in, const int* in_sizes, int n_in,
                              void* d_out, int out_size, void* d_ws, size_t ws_size,
                              hipStream_t stream) {
    const float* x_col = (const float*)d_in[0];
    const float* x_con = (const float*)d_in[1];
    const int* edge_col = (const int*)d_in[2];
    const int* edge_con = (const int*)d_in[3];
    const float* W_col = (const float*)d_in[4];
    const float* b_col = (const float*)d_in[5];
    const float* W_con = (const float*)d_in[6];
    const float* b_con = (const float*)d_in[7];
    const float* c1_cn_Wl = (const float*)d_in[8];
    const float* c1_cn_bl = (const float*)d_in[9];
    const float* c1_cn_Wr = (const float*)d_in[10];
    const float* c1_nc_Wl = (const float*)d_in[11];
    const float* c1_nc_bl = (const float*)d_in[12];
    const float* c1_nc_Wr = (const float*)d_in[13];
    // d_in[14..16] = c2_cn_* : dead (h_con2 deleted in reference)
    const float* c2_nc_Wl = (const float*)d_in[17];
    const float* c2_nc_bl = (const float*)d_in[18];
    const float* c2_nc_Wr = (const float*)d_in[19];
    const float* q_W1 = (const float*)d_in[20];
    const float* q_b1 = (const float*)d_in[21];
    const float* q_W2 = (const float*)d_in[22];
    const float* q_b2 = (const float*)d_in[23];
    float* out = (float*)d_out;
    const int E = in_sizes[2];

    float* ws = (float*)d_ws;
    size_t o = 0;
    float* h_col = ws + o;   o += (size_t)N_COL * HDIM;
    float* h_con = ws + o;   o += (size_t)N_CON * HDIM;
    float* n_con = ws + o;   o += (size_t)N_CON * HDIM;
    float* c01 = ws + o;     o += (size_t)N_COL * HDIM;   // gather(lin1(h_con))
    float* c02 = ws + o;     o += (size_t)N_COL * HDIM;   // gather(lin2(n_con))
    float* bufB = ws + o;    o += (size_t)N_CON * HDIM;   // transformed source tables (reused)
    float* W_colT = ws + o;  o += 16 * HDIM;
    float* W_conT = ws + o;  o += 8 * HDIM;
    float* c1_cn_WlT = ws + o; o += HDIM * HDIM;
    float* c1_cn_WrT = ws + o; o += HDIM * HDIM;
    float* c1_nc_WlT = ws + o; o += HDIM * HDIM;
    float* c1_nc_WrT = ws + o; o += HDIM * HDIM;
    float* c2_nc_WlT = ws + o; o += HDIM * HDIM;
    float* c2_nc_WrT = ws + o; o += HDIM * HDIM;
    float* q_W1T = ws + o;     o += HDIM * 64;
    // CSR scratch (int views)
    int* iws = (int*)(ws + o);
    size_t io = 0;
    int* cnt_col = iws + io;  io += N_COL;
    int* cnt_con = iws + io;  io += N_CON;
    int* offs_col = iws + io; io += N_COL;
    int* offs_con = iws + io; io += N_CON;
    int* cursor = iws + io;   io += N_COL;
    int* partials = iws + io; io += 256;
    int* srclist_col = iws + io; io += E;   // dst=col buckets, stores con src idx
    int* srclist_con = iws + io; io += E;   // dst=con buckets, stores col src idx

    auto T = [&](const float* s, float* d, int R, int C) {
        transpose_k<<<(R * C + 255) / 256, 256, 0, stream>>>(s, d, R, C);
    };
    T(W_col, W_colT, HDIM, 16);
    T(W_con, W_conT, HDIM, 8);
    T(c1_cn_Wl, c1_cn_WlT, HDIM, HDIM);
    T(c1_cn_Wr, c1_cn_WrT, HDIM, HDIM);
    T(c1_nc_Wl, c1_nc_WlT, HDIM, HDIM);
    T(c1_nc_Wr, c1_nc_WrT, HDIM, HDIM);
    T(c2_nc_Wl, c2_nc_WlT, HDIM, HDIM);
    T(c2_nc_Wr, c2_nc_WrT, HDIM, HDIM);
    T(q_W1, q_W1T, 64, HDIM);

    encoder_k<16><<<((size_t)N_COL * HDIM + 255) / 256, 256, 0, stream>>>(x_col, W_colT, b_col, h_col, N_COL);
    encoder_k<8><<<((size_t)N_CON * HDIM + 255) / 256, 256, 0, stream>>>(x_con, W_conT, b_con, h_con, N_CON);

    // ---- CSR build (both directions) ----
    hipMemsetAsync(cnt_col, 0, (N_COL + N_CON) * sizeof(int), stream);
    count_k<<<(E + 255) / 256, 256, 0, stream>>>(edge_col, edge_con, cnt_col, cnt_con, E);

    int nb_col = (N_COL + SCAN_B - 1) / SCAN_B;  // 98
    int nb_con = (N_CON + SCAN_B - 1) / SCAN_B;  // 20
    scan1_k<<<nb_col, 256, 0, stream>>>(cnt_col, N_COL, offs_col, partials);
    scan2_k<<<1, 256, 0, stream>>>(partials, nb_col);
    scan3_k<<<(N_COL + 255) / 256, 256, 0, stream>>>(offs_col, N_COL, partials);
    scan1_k<<<nb_con, 256, 0, stream>>>(cnt_con, N_CON, offs_con, partials);
    scan2_k<<<1, 256, 0, stream>>>(partials, nb_con);
    scan3_k<<<(N_CON + 255) / 256, 256, 0, stream>>>(offs_con, N_CON, partials);

    hipMemsetAsync(cursor, 0, N_COL * sizeof(int), stream);
    fill_k<<<(E + 255) / 256, 256, 0, stream>>>(edge_con, edge_col, offs_col, cursor, srclist_col, E);
    hipMemsetAsync(cursor, 0, N_CON * sizeof(int), stream);
    fill_k<<<(E + 255) / 256, 256, 0, stream>>>(edge_col, edge_con, offs_con, cursor, srclist_con, E);

    // ---- conv1 col->con (dst small: classic gather + dual GEMM) ----
    gather_mean_k<<<(N_CON + 3) / 4, 256, 0, stream>>>(h_col, srclist_con, offs_con, cnt_con, bufB, N_CON);
    sage_gemm_k<<<(N_CON + 63) / 64, 256, 0, stream>>>(bufB, h_con, c1_cn_WlT, c1_cn_bl, c1_cn_WrT, n_con, N_CON);

    // ---- col-direction gathered terms (linearity: gather(lin(src))) ----
    lin_k<<<(N_CON + 63) / 64, 256, 0, stream>>>(h_con, c1_nc_WlT, bufB, N_CON);
    gather_mean_k<<<(N_COL + 3) / 4, 256, 0, stream>>>(bufB, srclist_col, offs_col, cnt_col, c01, N_COL);
    lin_k<<<(N_CON + 63) / 64, 256, 0, stream>>>(n_con, c2_nc_WlT, bufB, N_CON);
    gather_mean_k<<<(N_COL + 3) / 4, 256, 0, stream>>>(bufB, srclist_col, offs_col, cnt_col, c02, N_COL);

    // ---- fused conv1-nc + conv2-nc + Q-head (n_col never hits global) ----
    col_mega_k<<<(N_COL + 63) / 64, 256, 0, stream>>>(c01, c02, h_col,
                                                      c1_nc_WrT, c1_nc_bl, c2_nc_WrT, c2_nc_bl,
                                                      q_W1T, q_b1, q_W2, q_b2, out, N_COL);
}

// Round 10
// 740.530 us; speedup vs baseline: 1.0305x; 1.0305x over previous
//
#include <hip/hip_runtime.h>

#define N_COL 100000
#define N_CON 20000
#define HDIM 128
#define SCAN_B 1024  // elements scanned per block (256 thr x 4)

// ---------- tiny transpose: dst[c*R+r] = src[r*C+c] ----------
__global__ void transpose_k(const float* __restrict__ src, float* __restrict__ dst, int R, int C) {
    int idx = blockIdx.x * blockDim.x + threadIdx.x;
    if (idx < R * C) {
        int r = idx / C, c = idx - r * C;
        dst[c * R + r] = src[idx];
    }
}

// ---------- encoder: out[n,h] = relu(sum_k x[n,k]*WT[k,h] + b[h]) ----------
template <int D>
__global__ __launch_bounds__(256) void encoder_k(const float* __restrict__ x,
                                                 const float* __restrict__ WT,
                                                 const float* __restrict__ b,
                                                 float* __restrict__ out, int N) {
    int idx = blockIdx.x * blockDim.x + threadIdx.x;
    if (idx >= N * HDIM) return;
    int n = idx >> 7, h = idx & 127;
    const float* xr = x + (size_t)n * D;
    float acc = b[h];
#pragma unroll
    for (int k = 0; k < D; k++) acc = fmaf(xr[k], WT[k * HDIM + h], acc);
    out[idx] = fmaxf(acc, 0.f);
}

// ---------- CSR build ----------
__global__ void count_k(const int* __restrict__ ecol, const int* __restrict__ econ,
                        int* cnt_col, int* cnt_con, int E) {
    int e = blockIdx.x * blockDim.x + threadIdx.x;
    if (e < E) {
        atomicAdd(&cnt_col[ecol[e]], 1);
        atomicAdd(&cnt_con[econ[e]], 1);
    }
}

__global__ __launch_bounds__(256) void scan1_k(const int* __restrict__ cnt, int n,
                                               int* __restrict__ offs, int* __restrict__ partials) {
    __shared__ int lds[256];
    int t = threadIdx.x;
    int base = blockIdx.x * SCAN_B + t * 4;
    int v[4], s = 0;
#pragma unroll
    for (int i = 0; i < 4; i++) { int idx = base + i; v[i] = (idx < n) ? cnt[idx] : 0; s += v[i]; }
    lds[t] = s; __syncthreads();
    for (int off = 1; off < 256; off <<= 1) {
        int x = (t >= off) ? lds[t - off] : 0; __syncthreads();
        lds[t] += x; __syncthreads();
    }
    int excl = lds[t] - s;
    if (t == 255) partials[blockIdx.x] = lds[255];
    int run = excl;
#pragma unroll
    for (int i = 0; i < 4; i++) { int idx = base + i; if (idx < n) offs[idx] = run; run += v[i]; }
}

__global__ __launch_bounds__(256) void scan2_k(int* partials, int nb) {
    __shared__ int lds[256];
    int t = threadIdx.x;
    int v = (t < nb) ? partials[t] : 0;
    lds[t] = v; __syncthreads();
    for (int off = 1; off < 256; off <<= 1) {
        int x = (t >= off) ? lds[t - off] : 0; __syncthreads();
        lds[t] += x; __syncthreads();
    }
    if (t < nb) partials[t] = lds[t] - v;
}

__global__ void scan3_k(int* offs, int n, const int* __restrict__ partials) {
    int i = blockIdx.x * blockDim.x + threadIdx.x;
    if (i < n) offs[i] += partials[i / SCAN_B];
}

__global__ void fill_k(const int* __restrict__ sidx, const int* __restrict__ didx,
                       const int* __restrict__ offs, int* cursor, int* __restrict__ srclist, int E) {
    int e = blockIdx.x * blockDim.x + threadIdx.x;
    if (e < E) {
        int d = didx[e];
        int p = offs[d] + atomicAdd(&cursor[d], 1);
        srclist[p] = sidx[e];
    }
}

// ---------- gather segment-mean: one wave per dst node (single table) ----------
__global__ __launch_bounds__(256) void gather_mean_k(const float* __restrict__ tab,
                                                     const int* __restrict__ srclist,
                                                     const int* __restrict__ offs,
                                                     const int* __restrict__ cnt,
                                                     float* __restrict__ out, int N) {
    int wid = threadIdx.x >> 6, lane = threadIdx.x & 63;
    int n = blockIdx.x * 4 + wid;
    if (n >= N) return;
    int c = cnt[n], st = offs[n];
    const int* sl = srclist + st;
    int half = lane >> 5, q = (lane & 31) * 4;
    float ax = 0.f, ay = 0.f, az = 0.f, aw = 0.f;
    int j = 0;
    for (; j + 1 < c; j += 2) {
        int s = sl[j + half];
        float4 a = *reinterpret_cast<const float4*>(tab + (size_t)s * HDIM + q);
        ax += a.x; ay += a.y; az += a.z; aw += a.w;
    }
    if (j < c && half == 0) {
        int s = sl[j];
        float4 a = *reinterpret_cast<const float4*>(tab + (size_t)s * HDIM + q);
        ax += a.x; ay += a.y; az += a.z; aw += a.w;
    }
    ax += __shfl_xor(ax, 32); ay += __shfl_xor(ay, 32);
    az += __shfl_xor(az, 32); aw += __shfl_xor(aw, 32);
    if (half == 0) {
        float inv = 1.f / fmaxf((float)c, 1.f);
        float4 r; r.x = ax * inv; r.y = ay * inv; r.z = az * inv; r.w = aw * inv;
        *reinterpret_cast<float4*>(out + (size_t)n * HDIM + q) = r;
    }
}

// ---------- dual gather: half-wave 0 gathers t1->o1, half-wave 1 gathers t2->o2 ----------
// One index-list traversal serves both col-direction convs.
__global__ __launch_bounds__(256) void gather_dual_k(const float* __restrict__ t1,
                                                     const float* __restrict__ t2,
                                                     const int* __restrict__ srclist,
                                                     const int* __restrict__ offs,
                                                     const int* __restrict__ cnt,
                                                     float* __restrict__ o1,
                                                     float* __restrict__ o2, int N) {
    int wid = threadIdx.x >> 6, lane = threadIdx.x & 63;
    int n = blockIdx.x * 4 + wid;
    if (n >= N) return;
    int c = cnt[n], st = offs[n];
    const int* sl = srclist + st;
    int half = lane >> 5, q = (lane & 31) * 4;
    const float* tab = half ? t2 : t1;
    float ax = 0.f, ay = 0.f, az = 0.f, aw = 0.f;
    int j = 0;
    for (; j + 1 < c; j += 2) {
        int s0 = sl[j], s1 = sl[j + 1];
        float4 a = *reinterpret_cast<const float4*>(tab + (size_t)s0 * HDIM + q);
        float4 b = *reinterpret_cast<const float4*>(tab + (size_t)s1 * HDIM + q);
        ax += a.x + b.x; ay += a.y + b.y; az += a.z + b.z; aw += a.w + b.w;
    }
    if (j < c) {
        int s0 = sl[j];
        float4 a = *reinterpret_cast<const float4*>(tab + (size_t)s0 * HDIM + q);
        ax += a.x; ay += a.y; az += a.z; aw += a.w;
    }
    float inv = 1.f / fmaxf((float)c, 1.f);
    float4 r; r.x = ax * inv; r.y = ay * inv; r.z = az * inv; r.w = aw * inv;
    float* op = (half ? o2 : o1) + (size_t)n * HDIM + q;
    *reinterpret_cast<float4*>(op) = r;
}

// ======== GEMM core: one K=128 pass, global A staged via As, float4 A reads ========
__device__ __forceinline__ void gemm_core(float (*As)[36], float (*Ws)[132],
                                          const float* __restrict__ src,
                                          const float* __restrict__ W,
                                          int n0, int N, int t, float acc[4][8]) {
    int tx = t & 15, ty = t >> 4;
    int ar = t >> 2, akq = (t & 3) * 8;
    int wk = t >> 3, wc = (t & 7) * 16;
    for (int kb = 0; kb < 4; ++kb) {
        int k0 = kb * 32;
        {
            int row = n0 + ar;
            float4 v0 = make_float4(0.f, 0.f, 0.f, 0.f), v1 = v0;
            if (row < N) {
                const float* ap = src + (size_t)row * HDIM + k0 + akq;
                v0 = *reinterpret_cast<const float4*>(ap);
                v1 = *reinterpret_cast<const float4*>(ap + 4);
            }
            *reinterpret_cast<float4*>(&As[ar][akq]) = v0;
            *reinterpret_cast<float4*>(&As[ar][akq + 4]) = v1;
        }
        {
            const float* wp = W + (size_t)(k0 + wk) * HDIM + wc;
#pragma unroll
            for (int jj = 0; jj < 4; jj++)
                *reinterpret_cast<float4*>(&Ws[wk][wc + 4 * jj]) =
                    *reinterpret_cast<const float4*>(wp + 4 * jj);
        }
        __syncthreads();
#pragma unroll
        for (int k4 = 0; k4 < 8; ++k4) {
            float4 av[4];
#pragma unroll
            for (int i = 0; i < 4; i++)
                av[i] = *reinterpret_cast<const float4*>(&As[ty * 4 + i][k4 * 4]);
#pragma unroll
            for (int kk = 0; kk < 4; kk++) {
                float4 w0 = *reinterpret_cast<const float4*>(&Ws[k4 * 4 + kk][tx * 4]);
                float4 w1 = *reinterpret_cast<const float4*>(&Ws[k4 * 4 + kk][64 + tx * 4]);
                float w[8] = {w0.x, w0.y, w0.z, w0.w, w1.x, w1.y, w1.z, w1.w};
#pragma unroll
                for (int i = 0; i < 4; i++) {
                    float avk = (kk == 0) ? av[i].x : (kk == 1) ? av[i].y
                                : (kk == 2) ? av[i].z : av[i].w;
#pragma unroll
                    for (int j = 0; j < 8; j++) acc[i][j] = fmaf(avk, w[j], acc[i][j]);
                }
            }
        }
        __syncthreads();
    }
}

// ======== GEMM core with A resident in LDS (H[64][132]) — no A staging ========
__device__ __forceinline__ void gemm_core_h(float (*Ha)[132], float (*Ws)[132],
                                            const float* __restrict__ W,
                                            int t, float acc[4][8]) {
    int tx = t & 15, ty = t >> 4;
    int wk = t >> 3, wc = (t & 7) * 16;
    for (int kb = 0; kb < 4; ++kb) {
        int k0 = kb * 32;
        {
            const float* wp = W + (size_t)(k0 + wk) * HDIM + wc;
#pragma unroll
            for (int jj = 0; jj < 4; jj++)
                *reinterpret_cast<float4*>(&Ws[wk][wc + 4 * jj]) =
                    *reinterpret_cast<const float4*>(wp + 4 * jj);
        }
        __syncthreads();
#pragma unroll
        for (int k4 = 0; k4 < 8; ++k4) {
            float4 av[4];
#pragma unroll
            for (int i = 0; i < 4; i++)
                av[i] = *reinterpret_cast<const float4*>(&Ha[ty * 4 + i][k0 + k4 * 4]);
#pragma unroll
            for (int kk = 0; kk < 4; kk++) {
                float4 w0 = *reinterpret_cast<const float4*>(&Ws[k4 * 4 + kk][tx * 4]);
                float4 w1 = *reinterpret_cast<const float4*>(&Ws[k4 * 4 + kk][64 + tx * 4]);
                float w[8] = {w0.x, w0.y, w0.z, w0.w, w1.x, w1.y, w1.z, w1.w};
#pragma unroll
                for (int i = 0; i < 4; i++) {
                    float avk = (kk == 0) ? av[i].x : (kk == 1) ? av[i].y
                                : (kk == 2) ? av[i].z : av[i].w;
#pragma unroll
                    for (int j = 0; j < 8; j++) acc[i][j] = fmaf(avk, w[j], acc[i][j]);
                }
            }
        }
        __syncthreads();
    }
}

// ---------- lin_k: out = src @ WT (no bias/relu) ----------
__global__ __launch_bounds__(256) void lin_k(const float* __restrict__ src,
                                             const float* __restrict__ WT,
                                             float* __restrict__ out, int N) {
    __shared__ __align__(16) float As[64][36];
    __shared__ __align__(16) float Ws[32][132];
    int t = threadIdx.x;
    int tx = t & 15, ty = t >> 4;
    int n0 = blockIdx.x * 64;
    float acc[4][8];
#pragma unroll
    for (int i = 0; i < 4; i++)
#pragma unroll
        for (int j = 0; j < 8; j++) acc[i][j] = 0.f;
    gemm_core(As, Ws, src, WT, n0, N, t, acc);
#pragma unroll
    for (int i = 0; i < 4; i++) {
        int row = n0 + ty * 4 + i;
        if (row < N) {
            float* op = out + (size_t)row * HDIM;
            *reinterpret_cast<float4*>(op + tx * 4) = make_float4(acc[i][0], acc[i][1], acc[i][2], acc[i][3]);
            *reinterpret_cast<float4*>(op + 64 + tx * 4) = make_float4(acc[i][4], acc[i][5], acc[i][6], acc[i][7]);
        }
    }
}

// ---------- dual-GEMM SAGE post (dst=con): out = relu(agg@WlT + x@WrT + bl) ----------
__global__ __launch_bounds__(256) void sage_gemm_k(const float* __restrict__ agg,
                                                   const float* __restrict__ xdst,
                                                   const float* __restrict__ WlT,
                                                   const float* __restrict__ bl,
                                                   const float* __restrict__ WrT,
                                                   float* __restrict__ out, int N) {
    __shared__ __align__(16) float As[64][36];
    __shared__ __align__(16) float Ws[32][132];
    int t = threadIdx.x;
    int tx = t & 15, ty = t >> 4;
    int n0 = blockIdx.x * 64;
    float acc[4][8];
#pragma unroll
    for (int i = 0; i < 4; i++)
#pragma unroll
        for (int j = 0; j < 8; j++) acc[i][j] = 0.f;
    gemm_core(As, Ws, agg, WlT, n0, N, t, acc);
    gemm_core(As, Ws, xdst, WrT, n0, N, t, acc);
    float4 b0 = *reinterpret_cast<const float4*>(bl + tx * 4);
    float4 b1 = *reinterpret_cast<const float4*>(bl + 64 + tx * 4);
    float bb[8] = {b0.x, b0.y, b0.z, b0.w, b1.x, b1.y, b1.z, b1.w};
#pragma unroll
    for (int i = 0; i < 4; i++) {
        int row = n0 + ty * 4 + i;
        if (row < N) {
            float4 r0, r1;
            r0.x = fmaxf(acc[i][0] + bb[0], 0.f);
            r0.y = fmaxf(acc[i][1] + bb[1], 0.f);
            r0.z = fmaxf(acc[i][2] + bb[2], 0.f);
            r0.w = fmaxf(acc[i][3] + bb[3], 0.f);
            r1.x = fmaxf(acc[i][4] + bb[4], 0.f);
            r1.y = fmaxf(acc[i][5] + bb[5], 0.f);
            r1.z = fmaxf(acc[i][6] + bb[6], 0.f);
            r1.w = fmaxf(acc[i][7] + bb[7], 0.f);
            float* op = out + (size_t)row * HDIM;
            *reinterpret_cast<float4*>(op + tx * 4) = r0;
            *reinterpret_cast<float4*>(op + 64 + tx * 4) = r1;
        }
    }
}

// ---------- col mega-kernel: conv1-nc + conv2-nc + Q-head; A lives in H (LDS 50688 -> 3 blk/CU) ----------
__global__ __launch_bounds__(256) void col_mega_k(const float* __restrict__ c0_1,
                                                  const float* __restrict__ c0_2,
                                                  const float* __restrict__ xdst,
                                                  const float* __restrict__ Wr1T,
                                                  const float* __restrict__ bl1,
                                                  const float* __restrict__ Wr2T,
                                                  const float* __restrict__ bl2,
                                                  const float* __restrict__ W1T,
                                                  const float* __restrict__ b1v,
                                                  const float* __restrict__ W2,
                                                  const float* __restrict__ b2,
                                                  float* __restrict__ out, int N) {
    __shared__ __align__(16) char smem[50688];  // H 33792 + Ws 16896
    float (*H)[132] = reinterpret_cast<float(*)[132]>(smem);
    float (*Ws)[132] = reinterpret_cast<float(*)[132]>(smem + 33792);
    int t = threadIdx.x;
    int tx = t & 15, ty = t >> 4;
    int n0 = blockIdx.x * 64;

    // stage h_col tile into H once (GEMM1 reads A from LDS)
    {
        int xr = t >> 2, xc0 = (t & 3) * 32;
        int row = n0 + xr;
        if (row < N) {
            const float* xp = xdst + (size_t)row * HDIM + xc0;
#pragma unroll
            for (int jj = 0; jj < 8; jj++)
                *reinterpret_cast<float4*>(&H[xr][xc0 + 4 * jj]) =
                    *reinterpret_cast<const float4*>(xp + 4 * jj);
        } else {
            float4 z = make_float4(0.f, 0.f, 0.f, 0.f);
#pragma unroll
            for (int jj = 0; jj < 8; jj++)
                *reinterpret_cast<float4*>(&H[xr][xc0 + 4 * jj]) = z;
        }
    }
    // (gemm_core_h's first barrier orders H-writes before H-reads)
    float acc[4][8];
#pragma unroll
    for (int i = 0; i < 4; i++)
#pragma unroll
        for (int j = 0; j < 8; j++) acc[i][j] = 0.f;
    gemm_core_h(H, Ws, Wr1T, t, acc);
    // epilogue 1: n_col tile = relu(acc + c0_1 + bl1) -> overwrite H (GEMM1 reads done at its last barrier)
    {
        float4 b0 = *reinterpret_cast<const float4*>(bl1 + tx * 4);
        float4 b1 = *reinterpret_cast<const float4*>(bl1 + 64 + tx * 4);
        float bb[8] = {b0.x, b0.y, b0.z, b0.w, b1.x, b1.y, b1.z, b1.w};
#pragma unroll
        for (int i = 0; i < 4; i++) {
            int row = n0 + ty * 4 + i;
            float4 ca = make_float4(0.f, 0.f, 0.f, 0.f), cb = ca;
            if (row < N) {
                const float* cp = c0_1 + (size_t)row * HDIM;
                ca = *reinterpret_cast<const float4*>(cp + tx * 4);
                cb = *reinterpret_cast<const float4*>(cp + 64 + tx * 4);
            }
            float* hp = &H[ty * 4 + i][0];
            *reinterpret_cast<float4*>(hp + tx * 4) = make_float4(
                fmaxf(acc[i][0] + ca.x + bb[0], 0.f), fmaxf(acc[i][1] + ca.y + bb[1], 0.f),
                fmaxf(acc[i][2] + ca.z + bb[2], 0.f), fmaxf(acc[i][3] + ca.w + bb[3], 0.f));
            *reinterpret_cast<float4*>(hp + 64 + tx * 4) = make_float4(
                fmaxf(acc[i][4] + cb.x + bb[4], 0.f), fmaxf(acc[i][5] + cb.y + bb[5], 0.f),
                fmaxf(acc[i][6] + cb.z + bb[6], 0.f), fmaxf(acc[i][7] + cb.w + bb[7], 0.f));
        }
    }
    // GEMM2: h_col2 tile, A from LDS H (its first barrier orders epilogue-1 writes)
#pragma unroll
    for (int i = 0; i < 4; i++)
#pragma unroll
        for (int j = 0; j < 8; j++) acc[i][j] = 0.f;
    gemm_core_h(H, Ws, Wr2T, t, acc);
    // epilogue 2: H2 = relu(acc + c0_2 + bl2) -> overwrite H
    {
        float4 b0 = *reinterpret_cast<const float4*>(bl2 + tx * 4);
        float4 b1 = *reinterpret_cast<const float4*>(bl2 + 64 + tx * 4);
        float bb[8] = {b0.x, b0.y, b0.z, b0.w, b1.x, b1.y, b1.z, b1.w};
#pragma unroll
        for (int i = 0; i < 4; i++) {
            int row = n0 + ty * 4 + i;
            float4 ca = make_float4(0.f, 0.f, 0.f, 0.f), cb = ca;
            if (row < N) {
                const float* cp = c0_2 + (size_t)row * HDIM;
                ca = *reinterpret_cast<const float4*>(cp + tx * 4);
                cb = *reinterpret_cast<const float4*>(cp + 64 + tx * 4);
            }
            float* hp = &H[ty * 4 + i][0];
            *reinterpret_cast<float4*>(hp + tx * 4) = make_float4(
                fmaxf(acc[i][0] + ca.x + bb[0], 0.f), fmaxf(acc[i][1] + ca.y + bb[1], 0.f),
                fmaxf(acc[i][2] + ca.z + bb[2], 0.f), fmaxf(acc[i][3] + ca.w + bb[3], 0.f));
            *reinterpret_cast<float4*>(hp + 64 + tx * 4) = make_float4(
                fmaxf(acc[i][4] + cb.x + bb[4], 0.f), fmaxf(acc[i][5] + cb.y + bb[5], 0.f),
                fmaxf(acc[i][6] + cb.z + bb[6], 0.f), fmaxf(acc[i][7] + cb.w + bb[7], 0.f));
        }
    }
    __syncthreads();

    // Q-head: y = relu(H@W1T + b1) [64x64]; q = y@W2 + b2
    int tx2 = t & 7, ty2 = t >> 3;
    float acc2[2][8];
#pragma unroll
    for (int i = 0; i < 2; i++)
#pragma unroll
        for (int j = 0; j < 8; j++) acc2[i][j] = 0.f;
    for (int k4 = 0; k4 < HDIM / 4; ++k4) {
        float4 a0 = *reinterpret_cast<const float4*>(&H[ty2 * 2 + 0][k4 * 4]);
        float4 a1 = *reinterpret_cast<const float4*>(&H[ty2 * 2 + 1][k4 * 4]);
        float a[2][4] = {{a0.x, a0.y, a0.z, a0.w}, {a1.x, a1.y, a1.z, a1.w}};
#pragma unroll
        for (int kk = 0; kk < 4; kk++) {
            const float* wp = W1T + (size_t)(k4 * 4 + kk) * 64 + tx2 * 8;
            float4 w0 = *reinterpret_cast<const float4*>(wp);
            float4 w1 = *reinterpret_cast<const float4*>(wp + 4);
            float w[8] = {w0.x, w0.y, w0.z, w0.w, w1.x, w1.y, w1.z, w1.w};
#pragma unroll
            for (int i = 0; i < 2; i++)
#pragma unroll
                for (int j = 0; j < 8; j++) acc2[i][j] = fmaf(a[i][kk], w[j], acc2[i][j]);
        }
    }
    {
        float4 c0v = *reinterpret_cast<const float4*>(b1v + tx2 * 8);
        float4 c1v = *reinterpret_cast<const float4*>(b1v + tx2 * 8 + 4);
        float bb1[8] = {c0v.x, c0v.y, c0v.z, c0v.w, c1v.x, c1v.y, c1v.z, c1v.w};
        float4 d0 = *reinterpret_cast<const float4*>(W2 + tx2 * 8);
        float4 d1 = *reinterpret_cast<const float4*>(W2 + tx2 * 8 + 4);
        float w2[8] = {d0.x, d0.y, d0.z, d0.w, d1.x, d1.y, d1.z, d1.w};
#pragma unroll
        for (int i = 0; i < 2; i++) {
            float v = 0.f;
#pragma unroll
            for (int j = 0; j < 8; j++) v = fmaf(fmaxf(acc2[i][j] + bb1[j], 0.f), w2[j], v);
            v += __shfl_xor(v, 1);
            v += __shfl_xor(v, 2);
            v += __shfl_xor(v, 4);
            int row = n0 + ty2 * 2 + i;
            if (tx2 == 0 && row < N) out[row] = v + b2[0];
        }
    }
}

extern "C" void kernel_launch(void* const* d_in, const int* in_sizes, int n_in,
                              void* d_out, int out_size, void* d_ws, size_t ws_size,
                              hipStream_t stream) {
    const float* x_col = (const float*)d_in[0];
    const float* x_con = (const float*)d_in[1];
    const int* edge_col = (const int*)d_in[2];
    const int* edge_con = (const int*)d_in[3];
    const float* W_col = (const float*)d_in[4];
    const float* b_col = (const float*)d_in[5];
    const float* W_con = (const float*)d_in[6];
    const float* b_con = (const float*)d_in[7];
    const float* c1_cn_Wl = (const float*)d_in[8];
    const float* c1_cn_bl = (const float*)d_in[9];
    const float* c1_cn_Wr = (const float*)d_in[10];
    const float* c1_nc_Wl = (const float*)d_in[11];
    const float* c1_nc_bl = (const float*)d_in[12];
    const float* c1_nc_Wr = (const float*)d_in[13];
    // d_in[14..16] = c2_cn_* : dead (h_con2 deleted in reference)
    const float* c2_nc_Wl = (const float*)d_in[17];
    const float* c2_nc_bl = (const float*)d_in[18];
    const float* c2_nc_Wr = (const float*)d_in[19];
    const float* q_W1 = (const float*)d_in[20];
    const float* q_b1 = (const float*)d_in[21];
    const float* q_W2 = (const float*)d_in[22];
    const float* q_b2 = (const float*)d_in[23];
    float* out = (float*)d_out;
    const int E = in_sizes[2];

    float* ws = (float*)d_ws;
    size_t o = 0;
    float* h_col = ws + o;   o += (size_t)N_COL * HDIM;
    float* h_con = ws + o;   o += (size_t)N_CON * HDIM;   // aliased as buf2 after lin1
    float* n_con = ws + o;   o += (size_t)N_CON * HDIM;
    float* c01 = ws + o;     o += (size_t)N_COL * HDIM;   // gather(lin1(h_con))
    float* c02 = ws + o;     o += (size_t)N_COL * HDIM;   // gather(lin2(n_con))
    float* buf1 = ws + o;    o += (size_t)N_CON * HDIM;   // agg_con, then lin1 output
    float* W_colT = ws + o;  o += 16 * HDIM;
    float* W_conT = ws + o;  o += 8 * HDIM;
    float* c1_cn_WlT = ws + o; o += HDIM * HDIM;
    float* c1_cn_WrT = ws + o; o += HDIM * HDIM;
    float* c1_nc_WlT = ws + o; o += HDIM * HDIM;
    float* c1_nc_WrT = ws + o; o += HDIM * HDIM;
    float* c2_nc_WlT = ws + o; o += HDIM * HDIM;
    float* c2_nc_WrT = ws + o; o += HDIM * HDIM;
    float* q_W1T = ws + o;     o += HDIM * 64;
    // CSR scratch (int views)
    int* iws = (int*)(ws + o);
    size_t io = 0;
    int* cnt_col = iws + io;  io += N_COL;
    int* cnt_con = iws + io;  io += N_CON;
    int* offs_col = iws + io; io += N_COL;
    int* offs_con = iws + io; io += N_CON;
    int* cursor = iws + io;   io += N_COL;
    int* partials = iws + io; io += 256;
    int* srclist_col = iws + io; io += E;
    int* srclist_con = iws + io; io += E;
    float* buf2 = h_con;  // h_con dead after lin1 -> reuse for lin2 output

    auto T = [&](const float* s, float* d, int R, int C) {
        transpose_k<<<(R * C + 255) / 256, 256, 0, stream>>>(s, d, R, C);
    };
    T(W_col, W_colT, HDIM, 16);
    T(W_con, W_conT, HDIM, 8);
    T(c1_cn_Wl, c1_cn_WlT, HDIM, HDIM);
    T(c1_cn_Wr, c1_cn_WrT, HDIM, HDIM);
    T(c1_nc_Wl, c1_nc_WlT, HDIM, HDIM);
    T(c1_nc_Wr, c1_nc_WrT, HDIM, HDIM);
    T(c2_nc_Wl, c2_nc_WlT, HDIM, HDIM);
    T(c2_nc_Wr, c2_nc_WrT, HDIM, HDIM);
    T(q_W1, q_W1T, 64, HDIM);

    encoder_k<16><<<((size_t)N_COL * HDIM + 255) / 256, 256, 0, stream>>>(x_col, W_colT, b_col, h_col, N_COL);
    encoder_k<8><<<((size_t)N_CON * HDIM + 255) / 256, 256, 0, stream>>>(x_con, W_conT, b_con, h_con, N_CON);

    // ---- CSR build (both directions) ----
    hipMemsetAsync(cnt_col, 0, (N_COL + N_CON) * sizeof(int), stream);
    count_k<<<(E + 255) / 256, 256, 0, stream>>>(edge_col, edge_con, cnt_col, cnt_con, E);

    int nb_col = (N_COL + SCAN_B - 1) / SCAN_B;  // 98
    int nb_con = (N_CON + SCAN_B - 1) / SCAN_B;  // 20
    scan1_k<<<nb_col, 256, 0, stream>>>(cnt_col, N_COL, offs_col, partials);
    scan2_k<<<1, 256, 0, stream>>>(partials, nb_col);
    scan3_k<<<(N_COL + 255) / 256, 256, 0, stream>>>(offs_col, N_COL, partials);
    scan1_k<<<nb_con, 256, 0, stream>>>(cnt_con, N_CON, offs_con, partials);
    scan2_k<<<1, 256, 0, stream>>>(partials, nb_con);
    scan3_k<<<(N_CON + 255) / 256, 256, 0, stream>>>(offs_con, N_CON, partials);

    hipMemsetAsync(cursor, 0, N_COL * sizeof(int), stream);
    fill_k<<<(E + 255) / 256, 256, 0, stream>>>(edge_con, edge_col, offs_col, cursor, srclist_col, E);
    hipMemsetAsync(cursor, 0, N_CON * sizeof(int), stream);
    fill_k<<<(E + 255) / 256, 256, 0, stream>>>(edge_col, edge_con, offs_con, cursor, srclist_con, E);

    // ---- conv1 col->con (classic gather + dual GEMM) ----
    gather_mean_k<<<(N_CON + 3) / 4, 256, 0, stream>>>(h_col, srclist_con, offs_con, cnt_con, buf1, N_CON);
    sage_gemm_k<<<(N_CON + 63) / 64, 256, 0, stream>>>(buf1, h_con, c1_cn_WlT, c1_cn_bl, c1_cn_WrT, n_con, N_CON);

    // ---- col-direction gathered terms via linearity, one dual-gather pass ----
    lin_k<<<(N_CON + 63) / 64, 256, 0, stream>>>(h_con, c1_nc_WlT, buf1, N_CON);
    lin_k<<<(N_CON + 63) / 64, 256, 0, stream>>>(n_con, c2_nc_WlT, buf2, N_CON);
    gather_dual_k<<<(N_COL + 3) / 4, 256, 0, stream>>>(buf1, buf2, srclist_col, offs_col, cnt_col,
                                                       c01, c02, N_COL);

    // ---- fused conv1-nc + conv2-nc + Q-head (n_col never hits global) ----
    col_mega_k<<<(N_COL + 63) / 64, 256, 0, stream>>>(c01, c02, h_col,
                                                      c1_nc_WrT, c1_nc_bl, c2_nc_WrT, c2_nc_bl,
                                                      q_W1T, q_b1, q_W2, q_b2, out, N_COL);
}

// Round 11
// 708.660 us; speedup vs baseline: 1.0768x; 1.0450x over previous
//
#include <hip/hip_runtime.h>

#define N_COL 100000
#define N_CON 20000
#define HDIM 128
#define SCAN_B 1024

// ---------- one-shot prep: all 9 weight transposes in a single dispatch ----------
// dst[c*R+r] = src[r*C+c] for each (src,dst,R,C) region.
__global__ __launch_bounds__(256) void prep_k(
    const float* W_col, float* W_colT, const float* W_con, float* W_conT,
    const float* a2, float* b2_, const float* a3, float* b3,
    const float* a4, float* b4, const float* a5, float* b5,
    const float* a6, float* b6, const float* a7, float* b7,
    const float* qW1, float* qW1T) {
    int i = blockIdx.x * blockDim.x + threadIdx.x;
#define TRANS(SRC, DST, R, C, CNT)                        \
    if (i < (CNT)) {                                      \
        int r = i / (C), c = i - r * (C);                 \
        DST[c * (R) + r] = SRC[i];                        \
        return;                                           \
    }                                                     \
    i -= (CNT);
    TRANS(W_col, W_colT, 128, 16, 2048)
    TRANS(W_con, W_conT, 128, 8, 1024)
    TRANS(a2, b2_, 128, 128, 16384)
    TRANS(a3, b3, 128, 128, 16384)
    TRANS(a4, b4, 128, 128, 16384)
    TRANS(a5, b5, 128, 128, 16384)
    TRANS(a6, b6, 128, 128, 16384)
    TRANS(a7, b7, 128, 128, 16384)
    TRANS(qW1, qW1T, 64, 128, 8192)
#undef TRANS
}

// ---------- encoder: out[n,h] = relu(sum_k x[n,k]*WT[k,h] + b[h]) ----------
template <int D>
__global__ __launch_bounds__(256) void encoder_k(const float* __restrict__ x,
                                                 const float* __restrict__ WT,
                                                 const float* __restrict__ b,
                                                 float* __restrict__ out, int N) {
    int idx = blockIdx.x * blockDim.x + threadIdx.x;
    if (idx >= N * HDIM) return;
    int n = idx >> 7, h = idx & 127;
    const float* xr = x + (size_t)n * D;
    float acc = b[h];
#pragma unroll
    for (int k = 0; k < D; k++) acc = fmaf(xr[k], WT[k * HDIM + h], acc);
    out[idx] = fmaxf(acc, 0.f);
}

// ---------- unified CSR: counts (col section [0,N_COL), con section [N_COL,+N_CON)) ----------
__global__ void count_k(const int* __restrict__ ecol, const int* __restrict__ econ,
                        int* cnt, int E) {
    int e = blockIdx.x * blockDim.x + threadIdx.x;
    if (e < E) {
        atomicAdd(&cnt[ecol[e]], 1);
        atomicAdd(&cnt[N_COL + econ[e]], 1);
    }
}

__global__ __launch_bounds__(256) void scan1_k(const int* __restrict__ cnt, int n,
                                               int* __restrict__ offs, int* __restrict__ partials) {
    __shared__ int lds[256];
    int t = threadIdx.x;
    int base = blockIdx.x * SCAN_B + t * 4;
    int v[4], s = 0;
#pragma unroll
    for (int i = 0; i < 4; i++) { int idx = base + i; v[i] = (idx < n) ? cnt[idx] : 0; s += v[i]; }
    lds[t] = s; __syncthreads();
    for (int off = 1; off < 256; off <<= 1) {
        int x = (t >= off) ? lds[t - off] : 0; __syncthreads();
        lds[t] += x; __syncthreads();
    }
    int excl = lds[t] - s;
    if (t == 255) partials[blockIdx.x] = lds[255];
    int run = excl;
#pragma unroll
    for (int i = 0; i < 4; i++) { int idx = base + i; if (idx < n) offs[idx] = run; run += v[i]; }
}

__global__ __launch_bounds__(256) void scan2_k(int* partials, int nb) {
    __shared__ int lds[256];
    int t = threadIdx.x;
    int v = (t < nb) ? partials[t] : 0;
    lds[t] = v; __syncthreads();
    for (int off = 1; off < 256; off <<= 1) {
        int x = (t >= off) ? lds[t - off] : 0; __syncthreads();
        lds[t] += x; __syncthreads();
    }
    if (t < nb) partials[t] = lds[t] - v;
}

__global__ void scan3_k(int* offs, int n, const int* __restrict__ partials) {
    int i = blockIdx.x * blockDim.x + threadIdx.x;
    if (i < n) offs[i] += partials[i / SCAN_B];
}

// ---------- unified fill: both directions, one edge-list pass, srclist[2E] ----------
__global__ void fill2_k(const int* __restrict__ ecol, const int* __restrict__ econ,
                        const int* __restrict__ offs, int* cursor, int* __restrict__ srclist, int E) {
    int e = blockIdx.x * blockDim.x + threadIdx.x;
    if (e < E) {
        int dc = ecol[e], dn = econ[e];
        int p1 = offs[dc] + atomicAdd(&cursor[dc], 1);
        srclist[p1] = dn;                  // col-dst bucket holds con src
        int p2 = offs[N_COL + dn] + atomicAdd(&cursor[N_COL + dn], 1);
        srclist[p2] = dc;                  // con-dst bucket holds col src
    }
}

// ---------- gather segment-mean (con path, single table) ----------
__global__ __launch_bounds__(256) void gather_mean_k(const float* __restrict__ tab,
                                                     const int* __restrict__ srclist,
                                                     const int* __restrict__ offs,
                                                     const int* __restrict__ cnt,
                                                     float* __restrict__ out, int N) {
    int wid = threadIdx.x >> 6, lane = threadIdx.x & 63;
    int n = blockIdx.x * 4 + wid;
    if (n >= N) return;
    int c = cnt[n], st = offs[n];
    const int* sl = srclist + st;
    int half = lane >> 5, q = (lane & 31) * 4;
    float ax = 0.f, ay = 0.f, az = 0.f, aw = 0.f;
    int j = 0;
    for (; j + 1 < c; j += 2) {
        int s = sl[j + half];
        float4 a = *reinterpret_cast<const float4*>(tab + (size_t)s * HDIM + q);
        ax += a.x; ay += a.y; az += a.z; aw += a.w;
    }
    if (j < c && half == 0) {
        int s = sl[j];
        float4 a = *reinterpret_cast<const float4*>(tab + (size_t)s * HDIM + q);
        ax += a.x; ay += a.y; az += a.z; aw += a.w;
    }
    ax += __shfl_xor(ax, 32); ay += __shfl_xor(ay, 32);
    az += __shfl_xor(az, 32); aw += __shfl_xor(aw, 32);
    if (half == 0) {
        float inv = 1.f / fmaxf((float)c, 1.f);
        float4 r; r.x = ax * inv; r.y = ay * inv; r.z = az * inv; r.w = aw * inv;
        *reinterpret_cast<float4*>(out + (size_t)n * HDIM + q) = r;
    }
}

// ---------- dual gather on the combined [N_CON][256] table: each edge reads 1 contiguous KB ----------
__global__ __launch_bounds__(256) void gather_dual_k(const float* __restrict__ tabC,
                                                     const int* __restrict__ srclist,
                                                     const int* __restrict__ offs,
                                                     const int* __restrict__ cnt,
                                                     float* __restrict__ c0C, int N) {
    int wid = threadIdx.x >> 6, lane = threadIdx.x & 63;
    int n = blockIdx.x * 4 + wid;
    if (n >= N) return;
    int c = cnt[n], st = offs[n];
    const int* sl = srclist + st;
    int q = (lane & 63) * 4;   // 64 lanes x float4 = 256 floats = full combined row
    float ax = 0.f, ay = 0.f, az = 0.f, aw = 0.f;
    int j = 0;
    for (; j + 1 < c; j += 2) {
        int s0 = sl[j], s1 = sl[j + 1];
        float4 a = *reinterpret_cast<const float4*>(tabC + (size_t)s0 * 256 + q);
        float4 b = *reinterpret_cast<const float4*>(tabC + (size_t)s1 * 256 + q);
        ax += a.x + b.x; ay += a.y + b.y; az += a.z + b.z; aw += a.w + b.w;
    }
    if (j < c) {
        int s0 = sl[j];
        float4 a = *reinterpret_cast<const float4*>(tabC + (size_t)s0 * 256 + q);
        ax += a.x; ay += a.y; az += a.z; aw += a.w;
    }
    float inv = 1.f / fmaxf((float)c, 1.f);
    float4 r; r.x = ax * inv; r.y = ay * inv; r.z = az * inv; r.w = aw * inv;
    *reinterpret_cast<float4*>(c0C + (size_t)n * 256 + q) = r;
}

// ======== GEMM core: K=128 pass, global A staged via As ========
__device__ __forceinline__ void gemm_core(float (*As)[36], float (*Ws)[132],
                                          const float* __restrict__ src,
                                          const float* __restrict__ W,
                                          int n0, int N, int t, float acc[4][8]) {
    int tx = t & 15, ty = t >> 4;
    int ar = t >> 2, akq = (t & 3) * 8;
    int wk = t >> 3, wc = (t & 7) * 16;
    for (int kb = 0; kb < 4; ++kb) {
        int k0 = kb * 32;
        {
            int row = n0 + ar;
            float4 v0 = make_float4(0.f, 0.f, 0.f, 0.f), v1 = v0;
            if (row < N) {
                const float* ap = src + (size_t)row * HDIM + k0 + akq;
                v0 = *reinterpret_cast<const float4*>(ap);
                v1 = *reinterpret_cast<const float4*>(ap + 4);
            }
            *reinterpret_cast<float4*>(&As[ar][akq]) = v0;
            *reinterpret_cast<float4*>(&As[ar][akq + 4]) = v1;
        }
        {
            const float* wp = W + (size_t)(k0 + wk) * HDIM + wc;
#pragma unroll
            for (int jj = 0; jj < 4; jj++)
                *reinterpret_cast<float4*>(&Ws[wk][wc + 4 * jj]) =
                    *reinterpret_cast<const float4*>(wp + 4 * jj);
        }
        __syncthreads();
#pragma unroll
        for (int k4 = 0; k4 < 8; ++k4) {
            float4 av[4];
#pragma unroll
            for (int i = 0; i < 4; i++)
                av[i] = *reinterpret_cast<const float4*>(&As[ty * 4 + i][k4 * 4]);
#pragma unroll
            for (int kk = 0; kk < 4; kk++) {
                float4 w0 = *reinterpret_cast<const float4*>(&Ws[k4 * 4 + kk][tx * 4]);
                float4 w1 = *reinterpret_cast<const float4*>(&Ws[k4 * 4 + kk][64 + tx * 4]);
                float w[8] = {w0.x, w0.y, w0.z, w0.w, w1.x, w1.y, w1.z, w1.w};
#pragma unroll
                for (int i = 0; i < 4; i++) {
                    float avk = (kk == 0) ? av[i].x : (kk == 1) ? av[i].y
                                : (kk == 2) ? av[i].z : av[i].w;
#pragma unroll
                    for (int j = 0; j < 8; j++) acc[i][j] = fmaf(avk, w[j], acc[i][j]);
                }
            }
        }
        __syncthreads();
    }
}

// ======== GEMM core with A resident in LDS (H[64][132]) ========
__device__ __forceinline__ void gemm_core_h(float (*Ha)[132], float (*Ws)[132],
                                            const float* __restrict__ W,
                                            int t, float acc[4][8]) {
    int tx = t & 15, ty = t >> 4;
    int wk = t >> 3, wc = (t & 7) * 16;
    for (int kb = 0; kb < 4; ++kb) {
        int k0 = kb * 32;
        {
            const float* wp = W + (size_t)(k0 + wk) * HDIM + wc;
#pragma unroll
            for (int jj = 0; jj < 4; jj++)
                *reinterpret_cast<float4*>(&Ws[wk][wc + 4 * jj]) =
                    *reinterpret_cast<const float4*>(wp + 4 * jj);
        }
        __syncthreads();
#pragma unroll
        for (int k4 = 0; k4 < 8; ++k4) {
            float4 av[4];
#pragma unroll
            for (int i = 0; i < 4; i++)
                av[i] = *reinterpret_cast<const float4*>(&Ha[ty * 4 + i][k0 + k4 * 4]);
#pragma unroll
            for (int kk = 0; kk < 4; kk++) {
                float4 w0 = *reinterpret_cast<const float4*>(&Ws[k4 * 4 + kk][tx * 4]);
                float4 w1 = *reinterpret_cast<const float4*>(&Ws[k4 * 4 + kk][64 + tx * 4]);
                float w[8] = {w0.x, w0.y, w0.z, w0.w, w1.x, w1.y, w1.z, w1.w};
#pragma unroll
                for (int i = 0; i < 4; i++) {
                    float avk = (kk == 0) ? av[i].x : (kk == 1) ? av[i].y
                                : (kk == 2) ? av[i].z : av[i].w;
#pragma unroll
                    for (int j = 0; j < 8; j++) acc[i][j] = fmaf(avk, w[j], acc[i][j]);
                }
            }
        }
        __syncthreads();
    }
}

// ---------- combined lin: y=0 -> h_con@W1 into cols 0-127; y=1 -> n_con@W2 into cols 128-255 ----------
__global__ __launch_bounds__(256) void lin2_k(const float* __restrict__ s1,
                                              const float* __restrict__ W1,
                                              const float* __restrict__ s2,
                                              const float* __restrict__ W2,
                                              float* __restrict__ outC, int N) {
    __shared__ __align__(16) float As[64][36];
    __shared__ __align__(16) float Ws[32][132];
    int t = threadIdx.x;
    int tx = t & 15, ty = t >> 4;
    int n0 = blockIdx.x * 64;
    const float* src = blockIdx.y ? s2 : s1;
    const float* W = blockIdx.y ? W2 : W1;
    int coff = blockIdx.y * 128;
    float acc[4][8];
#pragma unroll
    for (int i = 0; i < 4; i++)
#pragma unroll
        for (int j = 0; j < 8; j++) acc[i][j] = 0.f;
    gemm_core(As, Ws, src, W, n0, N, t, acc);
#pragma unroll
    for (int i = 0; i < 4; i++) {
        int row = n0 + ty * 4 + i;
        if (row < N) {
            float* op = outC + (size_t)row * 256 + coff;
            *reinterpret_cast<float4*>(op + tx * 4) = make_float4(acc[i][0], acc[i][1], acc[i][2], acc[i][3]);
            *reinterpret_cast<float4*>(op + 64 + tx * 4) = make_float4(acc[i][4], acc[i][5], acc[i][6], acc[i][7]);
        }
    }
}

// ---------- dual-GEMM SAGE post (dst=con) ----------
__global__ __launch_bounds__(256) void sage_gemm_k(const float* __restrict__ agg,
                                                   const float* __restrict__ xdst,
                                                   const float* __restrict__ WlT,
                                                   const float* __restrict__ bl,
                                                   const float* __restrict__ WrT,
                                                   float* __restrict__ out, int N) {
    __shared__ __align__(16) float As[64][36];
    __shared__ __align__(16) float Ws[32][132];
    int t = threadIdx.x;
    int tx = t & 15, ty = t >> 4;
    int n0 = blockIdx.x * 64;
    float acc[4][8];
#pragma unroll
    for (int i = 0; i < 4; i++)
#pragma unroll
        for (int j = 0; j < 8; j++) acc[i][j] = 0.f;
    gemm_core(As, Ws, agg, WlT, n0, N, t, acc);
    gemm_core(As, Ws, xdst, WrT, n0, N, t, acc);
    float4 b0 = *reinterpret_cast<const float4*>(bl + tx * 4);
    float4 b1 = *reinterpret_cast<const float4*>(bl + 64 + tx * 4);
    float bb[8] = {b0.x, b0.y, b0.z, b0.w, b1.x, b1.y, b1.z, b1.w};
#pragma unroll
    for (int i = 0; i < 4; i++) {
        int row = n0 + ty * 4 + i;
        if (row < N) {
            float4 r0, r1;
            r0.x = fmaxf(acc[i][0] + bb[0], 0.f);
            r0.y = fmaxf(acc[i][1] + bb[1], 0.f);
            r0.z = fmaxf(acc[i][2] + bb[2], 0.f);
            r0.w = fmaxf(acc[i][3] + bb[3], 0.f);
            r1.x = fmaxf(acc[i][4] + bb[4], 0.f);
            r1.y = fmaxf(acc[i][5] + bb[5], 0.f);
            r1.z = fmaxf(acc[i][6] + bb[6], 0.f);
            r1.w = fmaxf(acc[i][7] + bb[7], 0.f);
            float* op = out + (size_t)row * HDIM;
            *reinterpret_cast<float4*>(op + tx * 4) = r0;
            *reinterpret_cast<float4*>(op + 64 + tx * 4) = r1;
        }
    }
}

// ---------- col mega-kernel: inline col-encoder + conv1-nc + conv2-nc + Q-head ----------
// Phase E: H = relu(x_col_tile[64x16] @ W_colT + b_col)   (K=16 mini-GEMM, x tile = 4KB)
// Phase 1: H = relu(c0[:,0:128] + H@Wr1T + bl1)
// Phase 2: H = relu(c0[:,128:256] + H@Wr2T + bl2)
// Phase Q: out = relu(H@W1T + b1)@W2 + b2
__global__ __launch_bounds__(256) void col_mega_k(const float* __restrict__ c0C,
                                                  const float* __restrict__ xcol,
                                                  const float* __restrict__ WcT,
                                                  const float* __restrict__ bcol,
                                                  const float* __restrict__ Wr1T,
                                                  const float* __restrict__ bl1,
                                                  const float* __restrict__ Wr2T,
                                                  const float* __restrict__ bl2,
                                                  const float* __restrict__ W1T,
                                                  const float* __restrict__ b1v,
                                                  const float* __restrict__ W2,
                                                  const float* __restrict__ b2,
                                                  float* __restrict__ out, int N) {
    __shared__ __align__(16) char smem[50688];  // H 33792 + Ws 16896
    float (*H)[132] = reinterpret_cast<float(*)[132]>(smem);
    float (*Ws)[132] = reinterpret_cast<float(*)[132]>(smem + 33792);
    float (*Xs)[20] = reinterpret_cast<float(*)[20]>(smem + 33792);            // 5120 B
    float (*Wc)[132] = reinterpret_cast<float(*)[132]>(smem + 33792 + 5120);   // 8448 B
    int t = threadIdx.x;
    int tx = t & 15, ty = t >> 4;
    int n0 = blockIdx.x * 64;
    float acc[4][8];

    // ---- Phase E: stage x tile + W_col, mini-GEMM K=16 into H ----
    {
        int xr = t >> 2, xq = (t & 3) * 4;
        int row = n0 + xr;
        float4 xv = make_float4(0.f, 0.f, 0.f, 0.f);
        if (row < N) xv = *reinterpret_cast<const float4*>(xcol + (size_t)row * 16 + xq);
        *reinterpret_cast<float4*>(&Xs[xr][xq]) = xv;
        const float* wp = WcT + (t >> 4) * HDIM + (t & 15) * 8;
        *reinterpret_cast<float4*>(&Wc[t >> 4][(t & 15) * 8]) = *reinterpret_cast<const float4*>(wp);
        *reinterpret_cast<float4*>(&Wc[t >> 4][(t & 15) * 8 + 4]) = *reinterpret_cast<const float4*>(wp + 4);
    }
    __syncthreads();
#pragma unroll
    for (int i = 0; i < 4; i++)
#pragma unroll
        for (int j = 0; j < 8; j++) acc[i][j] = 0.f;
#pragma unroll
    for (int k = 0; k < 16; ++k) {
        float a[4];
#pragma unroll
        for (int i = 0; i < 4; i++) a[i] = Xs[ty * 4 + i][k];
        float4 w0 = *reinterpret_cast<const float4*>(&Wc[k][tx * 4]);
        float4 w1 = *reinterpret_cast<const float4*>(&Wc[k][64 + tx * 4]);
        float w[8] = {w0.x, w0.y, w0.z, w0.w, w1.x, w1.y, w1.z, w1.w};
#pragma unroll
        for (int i = 0; i < 4; i++)
#pragma unroll
            for (int j = 0; j < 8; j++) acc[i][j] = fmaf(a[i], w[j], acc[i][j]);
    }
    __syncthreads();   // Xs/Wc reads done before H writes could... (H disjoint, but keep order for Ws overwrite below)
    {
        float4 b0 = *reinterpret_cast<const float4*>(bcol + tx * 4);
        float4 b1 = *reinterpret_cast<const float4*>(bcol + 64 + tx * 4);
#pragma unroll
        for (int i = 0; i < 4; i++) {
            float* hp = &H[ty * 4 + i][0];
            *reinterpret_cast<float4*>(hp + tx * 4) = make_float4(
                fmaxf(acc[i][0] + b0.x, 0.f), fmaxf(acc[i][1] + b0.y, 0.f),
                fmaxf(acc[i][2] + b0.z, 0.f), fmaxf(acc[i][3] + b0.w, 0.f));
            *reinterpret_cast<float4*>(hp + 64 + tx * 4) = make_float4(
                fmaxf(acc[i][4] + b1.x, 0.f), fmaxf(acc[i][5] + b1.y, 0.f),
                fmaxf(acc[i][6] + b1.z, 0.f), fmaxf(acc[i][7] + b1.w, 0.f));
        }
    }
    __syncthreads();   // H complete before GEMM1 (whose Ws staging overwrites Xs/Wc)

    // ---- Phase 1 ----
#pragma unroll
    for (int i = 0; i < 4; i++)
#pragma unroll
        for (int j = 0; j < 8; j++) acc[i][j] = 0.f;
    gemm_core_h(H, Ws, Wr1T, t, acc);
    {
        float4 b0 = *reinterpret_cast<const float4*>(bl1 + tx * 4);
        float4 b1 = *reinterpret_cast<const float4*>(bl1 + 64 + tx * 4);
#pragma unroll
        for (int i = 0; i < 4; i++) {
            int row = n0 + ty * 4 + i;
            float4 ca = make_float4(0.f, 0.f, 0.f, 0.f), cb = ca;
            if (row < N) {
                const float* cp = c0C + (size_t)row * 256;
                ca = *reinterpret_cast<const float4*>(cp + tx * 4);
                cb = *reinterpret_cast<const float4*>(cp + 64 + tx * 4);
            }
            float* hp = &H[ty * 4 + i][0];
            *reinterpret_cast<float4*>(hp + tx * 4) = make_float4(
                fmaxf(acc[i][0] + ca.x + b0.x, 0.f), fmaxf(acc[i][1] + ca.y + b0.y, 0.f),
                fmaxf(acc[i][2] + ca.z + b0.z, 0.f), fmaxf(acc[i][3] + ca.w + b0.w, 0.f));
            *reinterpret_cast<float4*>(hp + 64 + tx * 4) = make_float4(
                fmaxf(acc[i][4] + cb.x + b1.x, 0.f), fmaxf(acc[i][5] + cb.y + b1.y, 0.f),
                fmaxf(acc[i][6] + cb.z + b1.z, 0.f), fmaxf(acc[i][7] + cb.w + b1.w, 0.f));
        }
    }

    // ---- Phase 2 ----
#pragma unroll
    for (int i = 0; i < 4; i++)
#pragma unroll
        for (int j = 0; j < 8; j++) acc[i][j] = 0.f;
    gemm_core_h(H, Ws, Wr2T, t, acc);
    {
        float4 b0 = *reinterpret_cast<const float4*>(bl2 + tx * 4);
        float4 b1 = *reinterpret_cast<const float4*>(bl2 + 64 + tx * 4);
#pragma unroll
        for (int i = 0; i < 4; i++) {
            int row = n0 + ty * 4 + i;
            float4 ca = make_float4(0.f, 0.f, 0.f, 0.f), cb = ca;
            if (row < N) {
                const float* cp = c0C + (size_t)row * 256 + 128;
                ca = *reinterpret_cast<const float4*>(cp + tx * 4);
                cb = *reinterpret_cast<const float4*>(cp + 64 + tx * 4);
            }
            float* hp = &H[ty * 4 + i][0];
            *reinterpret_cast<float4*>(hp + tx * 4) = make_float4(
                fmaxf(acc[i][0] + ca.x + b0.x, 0.f), fmaxf(acc[i][1] + ca.y + b0.y, 0.f),
                fmaxf(acc[i][2] + ca.z + b0.z, 0.f), fmaxf(acc[i][3] + ca.w + b0.w, 0.f));
            *reinterpret_cast<float4*>(hp + 64 + tx * 4) = make_float4(
                fmaxf(acc[i][4] + cb.x + b1.x, 0.f), fmaxf(acc[i][5] + cb.y + b1.y, 0.f),
                fmaxf(acc[i][6] + cb.z + b1.z, 0.f), fmaxf(acc[i][7] + cb.w + b1.w, 0.f));
        }
    }
    __syncthreads();

    // ---- Phase Q ----
    int tx2 = t & 7, ty2 = t >> 3;
    float acc2[2][8];
#pragma unroll
    for (int i = 0; i < 2; i++)
#pragma unroll
        for (int j = 0; j < 8; j++) acc2[i][j] = 0.f;
    for (int k4 = 0; k4 < HDIM / 4; ++k4) {
        float4 a0 = *reinterpret_cast<const float4*>(&H[ty2 * 2 + 0][k4 * 4]);
        float4 a1 = *reinterpret_cast<const float4*>(&H[ty2 * 2 + 1][k4 * 4]);
        float a[2][4] = {{a0.x, a0.y, a0.z, a0.w}, {a1.x, a1.y, a1.z, a1.w}};
#pragma unroll
        for (int kk = 0; kk < 4; kk++) {
            const float* wp = W1T + (size_t)(k4 * 4 + kk) * 64 + tx2 * 8;
            float4 w0 = *reinterpret_cast<const float4*>(wp);
            float4 w1 = *reinterpret_cast<const float4*>(wp + 4);
            float w[8] = {w0.x, w0.y, w0.z, w0.w, w1.x, w1.y, w1.z, w1.w};
#pragma unroll
            for (int i = 0; i < 2; i++)
#pragma unroll
                for (int j = 0; j < 8; j++) acc2[i][j] = fmaf(a[i][kk], w[j], acc2[i][j]);
        }
    }
    {
        float4 c0v = *reinterpret_cast<const float4*>(b1v + tx2 * 8);
        float4 c1v = *reinterpret_cast<const float4*>(b1v + tx2 * 8 + 4);
        float bb1[8] = {c0v.x, c0v.y, c0v.z, c0v.w, c1v.x, c1v.y, c1v.z, c1v.w};
        float4 d0 = *reinterpret_cast<const float4*>(W2 + tx2 * 8);
        float4 d1 = *reinterpret_cast<const float4*>(W2 + tx2 * 8 + 4);
        float w2[8] = {d0.x, d0.y, d0.z, d0.w, d1.x, d1.y, d1.z, d1.w};
#pragma unroll
        for (int i = 0; i < 2; i++) {
            float v = 0.f;
#pragma unroll
            for (int j = 0; j < 8; j++) v = fmaf(fmaxf(acc2[i][j] + bb1[j], 0.f), w2[j], v);
            v += __shfl_xor(v, 1);
            v += __shfl_xor(v, 2);
            v += __shfl_xor(v, 4);
            int row = n0 + ty2 * 2 + i;
            if (tx2 == 0 && row < N) out[row] = v + b2[0];
        }
    }
}

extern "C" void kernel_launch(void* const* d_in, const int* in_sizes, int n_in,
                              void* d_out, int out_size, void* d_ws, size_t ws_size,
                              hipStream_t stream) {
    const float* x_col = (const float*)d_in[0];
    const float* x_con = (const float*)d_in[1];
    const int* edge_col = (const int*)d_in[2];
    const int* edge_con = (const int*)d_in[3];
    const float* W_col = (const float*)d_in[4];
    const float* b_col = (const float*)d_in[5];
    const float* W_con = (const float*)d_in[6];
    const float* b_con = (const float*)d_in[7];
    const float* c1_cn_Wl = (const float*)d_in[8];
    const float* c1_cn_bl = (const float*)d_in[9];
    const float* c1_cn_Wr = (const float*)d_in[10];
    const float* c1_nc_Wl = (const float*)d_in[11];
    const float* c1_nc_bl = (const float*)d_in[12];
    const float* c1_nc_Wr = (const float*)d_in[13];
    // d_in[14..16] = c2_cn_* : dead (h_con2 deleted in reference)
    const float* c2_nc_Wl = (const float*)d_in[17];
    const float* c2_nc_bl = (const float*)d_in[18];
    const float* c2_nc_Wr = (const float*)d_in[19];
    const float* q_W1 = (const float*)d_in[20];
    const float* q_b1 = (const float*)d_in[21];
    const float* q_W2 = (const float*)d_in[22];
    const float* q_b2 = (const float*)d_in[23];
    float* out = (float*)d_out;
    const int E = in_sizes[2];

    float* ws = (float*)d_ws;
    size_t o = 0;
    float* h_col = ws + o;   o += (size_t)N_COL * HDIM;
    float* h_con = ws + o;   o += (size_t)N_CON * HDIM;
    float* n_con = ws + o;   o += (size_t)N_CON * HDIM;
    float* c0C = ws + o;     o += (size_t)N_COL * 256;    // combined gathered terms
    float* linC = ws + o;    o += (size_t)N_CON * 256;    // combined lin outputs
    float* buf1 = ws + o;    o += (size_t)N_CON * HDIM;   // agg_con
    float* W_colT = ws + o;  o += 16 * HDIM;
    float* W_conT = ws + o;  o += 8 * HDIM;
    float* c1_cn_WlT = ws + o; o += HDIM * HDIM;
    float* c1_cn_WrT = ws + o; o += HDIM * HDIM;
    float* c1_nc_WlT = ws + o; o += HDIM * HDIM;
    float* c1_nc_WrT = ws + o; o += HDIM * HDIM;
    float* c2_nc_WlT = ws + o; o += HDIM * HDIM;
    float* c2_nc_WrT = ws + o; o += HDIM * HDIM;
    float* q_W1T = ws + o;     o += HDIM * 64;
    // CSR scratch: cnt and cursor adjacent for one memset
    int* iws = (int*)(ws + o);
    size_t io = 0;
    int* cnt = iws + io;     io += N_COL + N_CON;
    int* cursor = iws + io;  io += N_COL + N_CON;
    int* offs = iws + io;    io += N_COL + N_CON;
    int* partials = iws + io; io += 256;
    int* srclist = iws + io; io += 2 * (size_t)E;
    const int NTOT = N_COL + N_CON;

    // all weight transposes, one dispatch (109568 elements)
    prep_k<<<(109568 + 255) / 256, 256, 0, stream>>>(
        W_col, W_colT, W_con, W_conT,
        c1_cn_Wl, c1_cn_WlT, c1_cn_Wr, c1_cn_WrT,
        c1_nc_Wl, c1_nc_WlT, c1_nc_Wr, c1_nc_WrT,
        c2_nc_Wl, c2_nc_WlT, c2_nc_Wr, c2_nc_WrT,
        q_W1, q_W1T);

    encoder_k<16><<<((size_t)N_COL * HDIM + 255) / 256, 256, 0, stream>>>(x_col, W_colT, b_col, h_col, N_COL);
    encoder_k<8><<<((size_t)N_CON * HDIM + 255) / 256, 256, 0, stream>>>(x_con, W_conT, b_con, h_con, N_CON);

    // ---- unified CSR build ----
    hipMemsetAsync(cnt, 0, 2 * NTOT * sizeof(int), stream);   // cnt + cursor
    count_k<<<(E + 255) / 256, 256, 0, stream>>>(edge_col, edge_con, cnt, E);
    int nb = (NTOT + SCAN_B - 1) / SCAN_B;  // 118
    scan1_k<<<nb, 256, 0, stream>>>(cnt, NTOT, offs, partials);
    scan2_k<<<1, 256, 0, stream>>>(partials, nb);
    scan3_k<<<(NTOT + 255) / 256, 256, 0, stream>>>(offs, NTOT, partials);
    fill2_k<<<(E + 255) / 256, 256, 0, stream>>>(edge_col, edge_con, offs, cursor, srclist, E);

    // ---- conv1 col->con ----
    gather_mean_k<<<(N_CON + 3) / 4, 256, 0, stream>>>(h_col, srclist, offs + N_COL, cnt + N_COL, buf1, N_CON);
    sage_gemm_k<<<(N_CON + 63) / 64, 256, 0, stream>>>(buf1, h_con, c1_cn_WlT, c1_cn_bl, c1_cn_WrT, n_con, N_CON);

    // ---- col-direction gathered terms: combined lin + one dual gather ----
    dim3 lgrid((N_CON + 63) / 64, 2);
    lin2_k<<<lgrid, 256, 0, stream>>>(h_con, c1_nc_WlT, n_con, c2_nc_WlT, linC, N_CON);
    gather_dual_k<<<(N_COL + 3) / 4, 256, 0, stream>>>(linC, srclist, offs, cnt, c0C, N_COL);

    // ---- fused encoder + conv1-nc + conv2-nc + Q-head ----
    col_mega_k<<<(N_COL + 63) / 64, 256, 0, stream>>>(c0C, x_col, W_colT, b_col,
                                                      c1_nc_WrT, c1_nc_bl, c2_nc_WrT, c2_nc_bl,
                                                      q_W1T, q_b1, q_W2, q_b2, out, N_COL);
}

// Round 12
// 629.804 us; speedup vs baseline: 1.2116x; 1.1252x over previous
//
#include <hip/hip_runtime.h>
#include <hip/hip_fp16.h>

#define N_COL 100000
#define N_CON 20000
#define HDIM 128
#define SCAN_B 1024

// ---- fp16 pack/unpack helpers (4 halves <-> float2 raw) ----
__device__ __forceinline__ float2 pack4h(float a, float b, float c, float d) {
    __half2 h0 = __float22half2_rn(make_float2(a, b));
    __half2 h1 = __float22half2_rn(make_float2(c, d));
    float2 r;
    r.x = *reinterpret_cast<float*>(&h0);
    r.y = *reinterpret_cast<float*>(&h1);
    return r;
}
__device__ __forceinline__ void unpack4h(float2 raw, float* o) {
    __half2 h0 = *reinterpret_cast<__half2*>(&raw.x);
    __half2 h1 = *reinterpret_cast<__half2*>(&raw.y);
    float2 f0 = __half22float2(h0), f1 = __half22float2(h1);
    o[0] = f0.x; o[1] = f0.y; o[2] = f1.x; o[3] = f1.y;
}

// ---------- one-shot prep: all 9 weight transposes in a single dispatch ----------
__global__ __launch_bounds__(256) void prep_k(
    const float* W_col, float* W_colT, const float* W_con, float* W_conT,
    const float* a2, float* b2_, const float* a3, float* b3,
    const float* a4, float* b4, const float* a5, float* b5,
    const float* a6, float* b6, const float* a7, float* b7,
    const float* qW1, float* qW1T) {
    int i = blockIdx.x * blockDim.x + threadIdx.x;
#define TRANS(SRC, DST, R, C, CNT)                        \
    if (i < (CNT)) {                                      \
        int r = i / (C), c = i - r * (C);                 \
        DST[c * (R) + r] = SRC[i];                        \
        return;                                           \
    }                                                     \
    i -= (CNT);
    TRANS(W_col, W_colT, 128, 16, 2048)
    TRANS(W_con, W_conT, 128, 8, 1024)
    TRANS(a2, b2_, 128, 128, 16384)
    TRANS(a3, b3, 128, 128, 16384)
    TRANS(a4, b4, 128, 128, 16384)
    TRANS(a5, b5, 128, 128, 16384)
    TRANS(a6, b6, 128, 128, 16384)
    TRANS(a7, b7, 128, 128, 16384)
    TRANS(qW1, qW1T, 64, 128, 8192)
#undef TRANS
}

// ---------- encoder: out[n,h] = relu(x@WT + b); OUT = float or __half ----------
template <int D, typename OUT>
__global__ __launch_bounds__(256) void encoder_k(const float* __restrict__ x,
                                                 const float* __restrict__ WT,
                                                 const float* __restrict__ b,
                                                 OUT* __restrict__ out, int N) {
    int idx = blockIdx.x * blockDim.x + threadIdx.x;
    if (idx >= N * HDIM) return;
    int n = idx >> 7, h = idx & 127;
    const float* xr = x + (size_t)n * D;
    float acc = b[h];
#pragma unroll
    for (int k = 0; k < D; k++) acc = fmaf(xr[k], WT[k * HDIM + h], acc);
    out[idx] = (OUT)fmaxf(acc, 0.f);
}

// ---------- unified CSR ----------
__global__ void count_k(const int* __restrict__ ecol, const int* __restrict__ econ,
                        int* cnt, int E) {
    int e = blockIdx.x * blockDim.x + threadIdx.x;
    if (e < E) {
        atomicAdd(&cnt[ecol[e]], 1);
        atomicAdd(&cnt[N_COL + econ[e]], 1);
    }
}

__global__ __launch_bounds__(256) void scan1_k(const int* __restrict__ cnt, int n,
                                               int* __restrict__ offs, int* __restrict__ partials) {
    __shared__ int lds[256];
    int t = threadIdx.x;
    int base = blockIdx.x * SCAN_B + t * 4;
    int v[4], s = 0;
#pragma unroll
    for (int i = 0; i < 4; i++) { int idx = base + i; v[i] = (idx < n) ? cnt[idx] : 0; s += v[i]; }
    lds[t] = s; __syncthreads();
    for (int off = 1; off < 256; off <<= 1) {
        int x = (t >= off) ? lds[t - off] : 0; __syncthreads();
        lds[t] += x; __syncthreads();
    }
    int excl = lds[t] - s;
    if (t == 255) partials[blockIdx.x] = lds[255];
    int run = excl;
#pragma unroll
    for (int i = 0; i < 4; i++) { int idx = base + i; if (idx < n) offs[idx] = run; run += v[i]; }
}

__global__ __launch_bounds__(256) void scan2_k(int* partials, int nb) {
    __shared__ int lds[256];
    int t = threadIdx.x;
    int v = (t < nb) ? partials[t] : 0;
    lds[t] = v; __syncthreads();
    for (int off = 1; off < 256; off <<= 1) {
        int x = (t >= off) ? lds[t - off] : 0; __syncthreads();
        lds[t] += x; __syncthreads();
    }
    if (t < nb) partials[t] = lds[t] - v;
}

__global__ void scan3_k(int* offs, int n, const int* __restrict__ partials) {
    int i = blockIdx.x * blockDim.x + threadIdx.x;
    if (i < n) offs[i] += partials[i / SCAN_B];
}

__global__ void fill2_k(const int* __restrict__ ecol, const int* __restrict__ econ,
                        const int* __restrict__ offs, int* cursor, int* __restrict__ srclist, int E) {
    int e = blockIdx.x * blockDim.x + threadIdx.x;
    if (e < E) {
        int dc = ecol[e], dn = econ[e];
        int p1 = offs[dc] + atomicAdd(&cursor[dc], 1);
        srclist[p1] = dn;
        int p2 = offs[N_COL + dn] + atomicAdd(&cursor[N_COL + dn], 1);
        srclist[p2] = dc;
    }
}

// ---------- gather segment-mean (con path) from fp16 table ----------
__global__ __launch_bounds__(256) void gather_mean_h_k(const __half* __restrict__ tab,
                                                       const int* __restrict__ srclist,
                                                       const int* __restrict__ offs,
                                                       const int* __restrict__ cnt,
                                                       float* __restrict__ out, int N) {
    int wid = threadIdx.x >> 6, lane = threadIdx.x & 63;
    int n = blockIdx.x * 4 + wid;
    if (n >= N) return;
    int c = cnt[n], st = offs[n];
    const int* sl = srclist + st;
    int half = lane >> 5, q = (lane & 31) * 4;
    float ax = 0.f, ay = 0.f, az = 0.f, aw = 0.f;
    int j = 0;
    for (; j + 1 < c; j += 2) {
        int s = sl[j + half];
        float2 raw = *reinterpret_cast<const float2*>(tab + (size_t)s * HDIM + q);
        float f[4]; unpack4h(raw, f);
        ax += f[0]; ay += f[1]; az += f[2]; aw += f[3];
    }
    if (j < c && half == 0) {
        int s = sl[j];
        float2 raw = *reinterpret_cast<const float2*>(tab + (size_t)s * HDIM + q);
        float f[4]; unpack4h(raw, f);
        ax += f[0]; ay += f[1]; az += f[2]; aw += f[3];
    }
    ax += __shfl_xor(ax, 32); ay += __shfl_xor(ay, 32);
    az += __shfl_xor(az, 32); aw += __shfl_xor(aw, 32);
    if (half == 0) {
        float inv = 1.f / fmaxf((float)c, 1.f);
        float4 r; r.x = ax * inv; r.y = ay * inv; r.z = az * inv; r.w = aw * inv;
        *reinterpret_cast<float4*>(out + (size_t)n * HDIM + q) = r;
    }
}

// ---------- dual gather on combined fp16 [N_CON][256] table -> fp16 c0C ----------
__global__ __launch_bounds__(256) void gather_dual_k(const __half* __restrict__ tabC,
                                                     const int* __restrict__ srclist,
                                                     const int* __restrict__ offs,
                                                     const int* __restrict__ cnt,
                                                     __half* __restrict__ c0C, int N) {
    int wid = threadIdx.x >> 6, lane = threadIdx.x & 63;
    int n = blockIdx.x * 4 + wid;
    if (n >= N) return;
    int c = cnt[n], st = offs[n];
    const int* sl = srclist + st;
    int q = lane * 4;   // 64 lanes x 4 halves = full 256-col row
    float ax = 0.f, ay = 0.f, az = 0.f, aw = 0.f;
    int j = 0;
    for (; j + 1 < c; j += 2) {
        int s0 = sl[j], s1 = sl[j + 1];
        float2 ra = *reinterpret_cast<const float2*>(tabC + (size_t)s0 * 256 + q);
        float2 rb = *reinterpret_cast<const float2*>(tabC + (size_t)s1 * 256 + q);
        float fa[4], fb[4]; unpack4h(ra, fa); unpack4h(rb, fb);
        ax += fa[0] + fb[0]; ay += fa[1] + fb[1]; az += fa[2] + fb[2]; aw += fa[3] + fb[3];
    }
    if (j < c) {
        int s0 = sl[j];
        float2 ra = *reinterpret_cast<const float2*>(tabC + (size_t)s0 * 256 + q);
        float fa[4]; unpack4h(ra, fa);
        ax += fa[0]; ay += fa[1]; az += fa[2]; aw += fa[3];
    }
    float inv = 1.f / fmaxf((float)c, 1.f);
    *reinterpret_cast<float2*>(c0C + (size_t)n * 256 + q) =
        pack4h(ax * inv, ay * inv, az * inv, aw * inv);
}

// ======== GEMM core: K=128 pass, global A staged via As ========
__device__ __forceinline__ void gemm_core(float (*As)[36], float (*Ws)[132],
                                          const float* __restrict__ src,
                                          const float* __restrict__ W,
                                          int n0, int N, int t, float acc[4][8]) {
    int tx = t & 15, ty = t >> 4;
    int ar = t >> 2, akq = (t & 3) * 8;
    int wk = t >> 3, wc = (t & 7) * 16;
    for (int kb = 0; kb < 4; ++kb) {
        int k0 = kb * 32;
        {
            int row = n0 + ar;
            float4 v0 = make_float4(0.f, 0.f, 0.f, 0.f), v1 = v0;
            if (row < N) {
                const float* ap = src + (size_t)row * HDIM + k0 + akq;
                v0 = *reinterpret_cast<const float4*>(ap);
                v1 = *reinterpret_cast<const float4*>(ap + 4);
            }
            *reinterpret_cast<float4*>(&As[ar][akq]) = v0;
            *reinterpret_cast<float4*>(&As[ar][akq + 4]) = v1;
        }
        {
            const float* wp = W + (size_t)(k0 + wk) * HDIM + wc;
#pragma unroll
            for (int jj = 0; jj < 4; jj++)
                *reinterpret_cast<float4*>(&Ws[wk][wc + 4 * jj]) =
                    *reinterpret_cast<const float4*>(wp + 4 * jj);
        }
        __syncthreads();
#pragma unroll
        for (int k4 = 0; k4 < 8; ++k4) {
            float4 av[4];
#pragma unroll
            for (int i = 0; i < 4; i++)
                av[i] = *reinterpret_cast<const float4*>(&As[ty * 4 + i][k4 * 4]);
#pragma unroll
            for (int kk = 0; kk < 4; kk++) {
                float4 w0 = *reinterpret_cast<const float4*>(&Ws[k4 * 4 + kk][tx * 4]);
                float4 w1 = *reinterpret_cast<const float4*>(&Ws[k4 * 4 + kk][64 + tx * 4]);
                float w[8] = {w0.x, w0.y, w0.z, w0.w, w1.x, w1.y, w1.z, w1.w};
#pragma unroll
                for (int i = 0; i < 4; i++) {
                    float avk = (kk == 0) ? av[i].x : (kk == 1) ? av[i].y
                                : (kk == 2) ? av[i].z : av[i].w;
#pragma unroll
                    for (int j = 0; j < 8; j++) acc[i][j] = fmaf(avk, w[j], acc[i][j]);
                }
            }
        }
        __syncthreads();
    }
}

// ======== GEMM core with A resident in LDS (H[64][132]) ========
__device__ __forceinline__ void gemm_core_h(float (*Ha)[132], float (*Ws)[132],
                                            const float* __restrict__ W,
                                            int t, float acc[4][8]) {
    int tx = t & 15, ty = t >> 4;
    int wk = t >> 3, wc = (t & 7) * 16;
    for (int kb = 0; kb < 4; ++kb) {
        int k0 = kb * 32;
        {
            const float* wp = W + (size_t)(k0 + wk) * HDIM + wc;
#pragma unroll
            for (int jj = 0; jj < 4; jj++)
                *reinterpret_cast<float4*>(&Ws[wk][wc + 4 * jj]) =
                    *reinterpret_cast<const float4*>(wp + 4 * jj);
        }
        __syncthreads();
#pragma unroll
        for (int k4 = 0; k4 < 8; ++k4) {
            float4 av[4];
#pragma unroll
            for (int i = 0; i < 4; i++)
                av[i] = *reinterpret_cast<const float4*>(&Ha[ty * 4 + i][k0 + k4 * 4]);
#pragma unroll
            for (int kk = 0; kk < 4; kk++) {
                float4 w0 = *reinterpret_cast<const float4*>(&Ws[k4 * 4 + kk][tx * 4]);
                float4 w1 = *reinterpret_cast<const float4*>(&Ws[k4 * 4 + kk][64 + tx * 4]);
                float w[8] = {w0.x, w0.y, w0.z, w0.w, w1.x, w1.y, w1.z, w1.w};
#pragma unroll
                for (int i = 0; i < 4; i++) {
                    float avk = (kk == 0) ? av[i].x : (kk == 1) ? av[i].y
                                : (kk == 2) ? av[i].z : av[i].w;
#pragma unroll
                    for (int j = 0; j < 8; j++) acc[i][j] = fmaf(avk, w[j], acc[i][j]);
                }
            }
        }
        __syncthreads();
    }
}

// ---------- combined lin -> fp16 table: y=0 h_con@W1 cols 0-127; y=1 n_con@W2 cols 128-255 ----------
__global__ __launch_bounds__(256) void lin2_k(const float* __restrict__ s1,
                                              const float* __restrict__ W1,
                                              const float* __restrict__ s2,
                                              const float* __restrict__ W2,
                                              __half* __restrict__ outC, int N) {
    __shared__ __align__(16) float As[64][36];
    __shared__ __align__(16) float Ws[32][132];
    int t = threadIdx.x;
    int tx = t & 15, ty = t >> 4;
    int n0 = blockIdx.x * 64;
    const float* src = blockIdx.y ? s2 : s1;
    const float* W = blockIdx.y ? W2 : W1;
    int coff = blockIdx.y * 128;
    float acc[4][8];
#pragma unroll
    for (int i = 0; i < 4; i++)
#pragma unroll
        for (int j = 0; j < 8; j++) acc[i][j] = 0.f;
    gemm_core(As, Ws, src, W, n0, N, t, acc);
#pragma unroll
    for (int i = 0; i < 4; i++) {
        int row = n0 + ty * 4 + i;
        if (row < N) {
            __half* op = outC + (size_t)row * 256 + coff;
            *reinterpret_cast<float2*>(op + tx * 4) =
                pack4h(acc[i][0], acc[i][1], acc[i][2], acc[i][3]);
            *reinterpret_cast<float2*>(op + 64 + tx * 4) =
                pack4h(acc[i][4], acc[i][5], acc[i][6], acc[i][7]);
        }
    }
}

// ---------- dual-GEMM SAGE post (dst=con) ----------
__global__ __launch_bounds__(256) void sage_gemm_k(const float* __restrict__ agg,
                                                   const float* __restrict__ xdst,
                                                   const float* __restrict__ WlT,
                                                   const float* __restrict__ bl,
                                                   const float* __restrict__ WrT,
                                                   float* __restrict__ out, int N) {
    __shared__ __align__(16) float As[64][36];
    __shared__ __align__(16) float Ws[32][132];
    int t = threadIdx.x;
    int tx = t & 15, ty = t >> 4;
    int n0 = blockIdx.x * 64;
    float acc[4][8];
#pragma unroll
    for (int i = 0; i < 4; i++)
#pragma unroll
        for (int j = 0; j < 8; j++) acc[i][j] = 0.f;
    gemm_core(As, Ws, agg, WlT, n0, N, t, acc);
    gemm_core(As, Ws, xdst, WrT, n0, N, t, acc);
    float4 b0 = *reinterpret_cast<const float4*>(bl + tx * 4);
    float4 b1 = *reinterpret_cast<const float4*>(bl + 64 + tx * 4);
    float bb[8] = {b0.x, b0.y, b0.z, b0.w, b1.x, b1.y, b1.z, b1.w};
#pragma unroll
    for (int i = 0; i < 4; i++) {
        int row = n0 + ty * 4 + i;
        if (row < N) {
            float4 r0, r1;
            r0.x = fmaxf(acc[i][0] + bb[0], 0.f);
            r0.y = fmaxf(acc[i][1] + bb[1], 0.f);
            r0.z = fmaxf(acc[i][2] + bb[2], 0.f);
            r0.w = fmaxf(acc[i][3] + bb[3], 0.f);
            r1.x = fmaxf(acc[i][4] + bb[4], 0.f);
            r1.y = fmaxf(acc[i][5] + bb[5], 0.f);
            r1.z = fmaxf(acc[i][6] + bb[6], 0.f);
            r1.w = fmaxf(acc[i][7] + bb[7], 0.f);
            float* op = out + (size_t)row * HDIM;
            *reinterpret_cast<float4*>(op + tx * 4) = r0;
            *reinterpret_cast<float4*>(op + 64 + tx * 4) = r1;
        }
    }
}

// ---------- col mega-kernel: inline encoder + conv1-nc + conv2-nc + Q-head; c0C is fp16 ----------
__global__ __launch_bounds__(256) void col_mega_k(const __half* __restrict__ c0C,
                                                  const float* __restrict__ xcol,
                                                  const float* __restrict__ WcT,
                                                  const float* __restrict__ bcol,
                                                  const float* __restrict__ Wr1T,
                                                  const float* __restrict__ bl1,
                                                  const float* __restrict__ Wr2T,
                                                  const float* __restrict__ bl2,
                                                  const float* __restrict__ W1T,
                                                  const float* __restrict__ b1v,
                                                  const float* __restrict__ W2,
                                                  const float* __restrict__ b2,
                                                  float* __restrict__ out, int N) {
    __shared__ __align__(16) char smem[50688];  // H 33792 + Ws 16896
    float (*H)[132] = reinterpret_cast<float(*)[132]>(smem);
    float (*Ws)[132] = reinterpret_cast<float(*)[132]>(smem + 33792);
    float (*Xs)[20] = reinterpret_cast<float(*)[20]>(smem + 33792);
    float (*Wc)[132] = reinterpret_cast<float(*)[132]>(smem + 33792 + 5120);
    int t = threadIdx.x;
    int tx = t & 15, ty = t >> 4;
    int n0 = blockIdx.x * 64;
    float acc[4][8];

    // ---- Phase E: inline col encoder (K=16) ----
    {
        int xr = t >> 2, xq = (t & 3) * 4;
        int row = n0 + xr;
        float4 xv = make_float4(0.f, 0.f, 0.f, 0.f);
        if (row < N) xv = *reinterpret_cast<const float4*>(xcol + (size_t)row * 16 + xq);
        *reinterpret_cast<float4*>(&Xs[xr][xq]) = xv;
        const float* wp = WcT + (t >> 4) * HDIM + (t & 15) * 8;
        *reinterpret_cast<float4*>(&Wc[t >> 4][(t & 15) * 8]) = *reinterpret_cast<const float4*>(wp);
        *reinterpret_cast<float4*>(&Wc[t >> 4][(t & 15) * 8 + 4]) = *reinterpret_cast<const float4*>(wp + 4);
    }
    __syncthreads();
#pragma unroll
    for (int i = 0; i < 4; i++)
#pragma unroll
        for (int j = 0; j < 8; j++) acc[i][j] = 0.f;
#pragma unroll
    for (int k = 0; k < 16; ++k) {
        float a[4];
#pragma unroll
        for (int i = 0; i < 4; i++) a[i] = Xs[ty * 4 + i][k];
        float4 w0 = *reinterpret_cast<const float4*>(&Wc[k][tx * 4]);
        float4 w1 = *reinterpret_cast<const float4*>(&Wc[k][64 + tx * 4]);
        float w[8] = {w0.x, w0.y, w0.z, w0.w, w1.x, w1.y, w1.z, w1.w};
#pragma unroll
        for (int i = 0; i < 4; i++)
#pragma unroll
            for (int j = 0; j < 8; j++) acc[i][j] = fmaf(a[i], w[j], acc[i][j]);
    }
    __syncthreads();
    {
        float4 b0 = *reinterpret_cast<const float4*>(bcol + tx * 4);
        float4 b1 = *reinterpret_cast<const float4*>(bcol + 64 + tx * 4);
#pragma unroll
        for (int i = 0; i < 4; i++) {
            float* hp = &H[ty * 4 + i][0];
            *reinterpret_cast<float4*>(hp + tx * 4) = make_float4(
                fmaxf(acc[i][0] + b0.x, 0.f), fmaxf(acc[i][1] + b0.y, 0.f),
                fmaxf(acc[i][2] + b0.z, 0.f), fmaxf(acc[i][3] + b0.w, 0.f));
            *reinterpret_cast<float4*>(hp + 64 + tx * 4) = make_float4(
                fmaxf(acc[i][4] + b1.x, 0.f), fmaxf(acc[i][5] + b1.y, 0.f),
                fmaxf(acc[i][6] + b1.z, 0.f), fmaxf(acc[i][7] + b1.w, 0.f));
        }
    }
    __syncthreads();

    // ---- Phase 1 ----
#pragma unroll
    for (int i = 0; i < 4; i++)
#pragma unroll
        for (int j = 0; j < 8; j++) acc[i][j] = 0.f;
    gemm_core_h(H, Ws, Wr1T, t, acc);
    {
        float4 b0 = *reinterpret_cast<const float4*>(bl1 + tx * 4);
        float4 b1 = *reinterpret_cast<const float4*>(bl1 + 64 + tx * 4);
#pragma unroll
        for (int i = 0; i < 4; i++) {
            int row = n0 + ty * 4 + i;
            float ca[4] = {0.f, 0.f, 0.f, 0.f}, cb[4] = {0.f, 0.f, 0.f, 0.f};
            if (row < N) {
                const __half* cp = c0C + (size_t)row * 256;
                unpack4h(*reinterpret_cast<const float2*>(cp + tx * 4), ca);
                unpack4h(*reinterpret_cast<const float2*>(cp + 64 + tx * 4), cb);
            }
            float* hp = &H[ty * 4 + i][0];
            *reinterpret_cast<float4*>(hp + tx * 4) = make_float4(
                fmaxf(acc[i][0] + ca[0] + b0.x, 0.f), fmaxf(acc[i][1] + ca[1] + b0.y, 0.f),
                fmaxf(acc[i][2] + ca[2] + b0.z, 0.f), fmaxf(acc[i][3] + ca[3] + b0.w, 0.f));
            *reinterpret_cast<float4*>(hp + 64 + tx * 4) = make_float4(
                fmaxf(acc[i][4] + cb[0] + b1.x, 0.f), fmaxf(acc[i][5] + cb[1] + b1.y, 0.f),
                fmaxf(acc[i][6] + cb[2] + b1.z, 0.f), fmaxf(acc[i][7] + cb[3] + b1.w, 0.f));
        }
    }

    // ---- Phase 2 ----
#pragma unroll
    for (int i = 0; i < 4; i++)
#pragma unroll
        for (int j = 0; j < 8; j++) acc[i][j] = 0.f;
    gemm_core_h(H, Ws, Wr2T, t, acc);
    {
        float4 b0 = *reinterpret_cast<const float4*>(bl2 + tx * 4);
        float4 b1 = *reinterpret_cast<const float4*>(bl2 + 64 + tx * 4);
#pragma unroll
        for (int i = 0; i < 4; i++) {
            int row = n0 + ty * 4 + i;
            float ca[4] = {0.f, 0.f, 0.f, 0.f}, cb[4] = {0.f, 0.f, 0.f, 0.f};
            if (row < N) {
                const __half* cp = c0C + (size_t)row * 256 + 128;
                unpack4h(*reinterpret_cast<const float2*>(cp + tx * 4), ca);
                unpack4h(*reinterpret_cast<const float2*>(cp + 64 + tx * 4), cb);
            }
            float* hp = &H[ty * 4 + i][0];
            *reinterpret_cast<float4*>(hp + tx * 4) = make_float4(
                fmaxf(acc[i][0] + ca[0] + b0.x, 0.f), fmaxf(acc[i][1] + ca[1] + b0.y, 0.f),
                fmaxf(acc[i][2] + ca[2] + b0.z, 0.f), fmaxf(acc[i][3] + ca[3] + b0.w, 0.f));
            *reinterpret_cast<float4*>(hp + 64 + tx * 4) = make_float4(
                fmaxf(acc[i][4] + cb[0] + b1.x, 0.f), fmaxf(acc[i][5] + cb[1] + b1.y, 0.f),
                fmaxf(acc[i][6] + cb[2] + b1.z, 0.f), fmaxf(acc[i][7] + cb[3] + b1.w, 0.f));
        }
    }
    __syncthreads();

    // ---- Phase Q ----
    int tx2 = t & 7, ty2 = t >> 3;
    float acc2[2][8];
#pragma unroll
    for (int i = 0; i < 2; i++)
#pragma unroll
        for (int j = 0; j < 8; j++) acc2[i][j] = 0.f;
    for (int k4 = 0; k4 < HDIM / 4; ++k4) {
        float4 a0 = *reinterpret_cast<const float4*>(&H[ty2 * 2 + 0][k4 * 4]);
        float4 a1 = *reinterpret_cast<const float4*>(&H[ty2 * 2 + 1][k4 * 4]);
        float a[2][4] = {{a0.x, a0.y, a0.z, a0.w}, {a1.x, a1.y, a1.z, a1.w}};
#pragma unroll
        for (int kk = 0; kk < 4; kk++) {
            const float* wp = W1T + (size_t)(k4 * 4 + kk) * 64 + tx2 * 8;
            float4 w0 = *reinterpret_cast<const float4*>(wp);
            float4 w1 = *reinterpret_cast<const float4*>(wp + 4);
            float w[8] = {w0.x, w0.y, w0.z, w0.w, w1.x, w1.y, w1.z, w1.w};
#pragma unroll
            for (int i = 0; i < 2; i++)
#pragma unroll
                for (int j = 0; j < 8; j++) acc2[i][j] = fmaf(a[i][kk], w[j], acc2[i][j]);
        }
    }
    {
        float4 c0v = *reinterpret_cast<const float4*>(b1v + tx2 * 8);
        float4 c1v = *reinterpret_cast<const float4*>(b1v + tx2 * 8 + 4);
        float bb1[8] = {c0v.x, c0v.y, c0v.z, c0v.w, c1v.x, c1v.y, c1v.z, c1v.w};
        float4 d0 = *reinterpret_cast<const float4*>(W2 + tx2 * 8);
        float4 d1 = *reinterpret_cast<const float4*>(W2 + tx2 * 8 + 4);
        float w2[8] = {d0.x, d0.y, d0.z, d0.w, d1.x, d1.y, d1.z, d1.w};
#pragma unroll
        for (int i = 0; i < 2; i++) {
            float v = 0.f;
#pragma unroll
            for (int j = 0; j < 8; j++) v = fmaf(fmaxf(acc2[i][j] + bb1[j], 0.f), w2[j], v);
            v += __shfl_xor(v, 1);
            v += __shfl_xor(v, 2);
            v += __shfl_xor(v, 4);
            int row = n0 + ty2 * 2 + i;
            if (tx2 == 0 && row < N) out[row] = v + b2[0];
        }
    }
}

extern "C" void kernel_launch(void* const* d_in, const int* in_sizes, int n_in,
                              void* d_out, int out_size, void* d_ws, size_t ws_size,
                              hipStream_t stream) {
    const float* x_col = (const float*)d_in[0];
    const float* x_con = (const float*)d_in[1];
    const int* edge_col = (const int*)d_in[2];
    const int* edge_con = (const int*)d_in[3];
    const float* W_col = (const float*)d_in[4];
    const float* b_col = (const float*)d_in[5];
    const float* W_con = (const float*)d_in[6];
    const float* b_con = (const float*)d_in[7];
    const float* c1_cn_Wl = (const float*)d_in[8];
    const float* c1_cn_bl = (const float*)d_in[9];
    const float* c1_cn_Wr = (const float*)d_in[10];
    const float* c1_nc_Wl = (const float*)d_in[11];
    const float* c1_nc_bl = (const float*)d_in[12];
    const float* c1_nc_Wr = (const float*)d_in[13];
    // d_in[14..16] = c2_cn_* : dead (h_con2 deleted in reference)
    const float* c2_nc_Wl = (const float*)d_in[17];
    const float* c2_nc_bl = (const float*)d_in[18];
    const float* c2_nc_Wr = (const float*)d_in[19];
    const float* q_W1 = (const float*)d_in[20];
    const float* q_b1 = (const float*)d_in[21];
    const float* q_W2 = (const float*)d_in[22];
    const float* q_b2 = (const float*)d_in[23];
    float* out = (float*)d_out;
    const int E = in_sizes[2];

    float* ws = (float*)d_ws;
    size_t o = 0;
    __half* h_colh = (__half*)(ws + o); o += (size_t)N_COL * HDIM / 2;  // fp16 table
    float* h_con = ws + o;   o += (size_t)N_CON * HDIM;
    float* n_con = ws + o;   o += (size_t)N_CON * HDIM;
    __half* c0C = (__half*)(ws + o); o += (size_t)N_COL * 256 / 2;      // fp16 combined gathered terms
    __half* linC = (__half*)(ws + o); o += (size_t)N_CON * 256 / 2;     // fp16 combined lin outputs
    float* buf1 = ws + o;    o += (size_t)N_CON * HDIM;                 // agg_con (fp32)
    float* W_colT = ws + o;  o += 16 * HDIM;
    float* W_conT = ws + o;  o += 8 * HDIM;
    float* c1_cn_WlT = ws + o; o += HDIM * HDIM;
    float* c1_cn_WrT = ws + o; o += HDIM * HDIM;
    float* c1_nc_WlT = ws + o; o += HDIM * HDIM;
    float* c1_nc_WrT = ws + o; o += HDIM * HDIM;
    float* c2_nc_WlT = ws + o; o += HDIM * HDIM;
    float* c2_nc_WrT = ws + o; o += HDIM * HDIM;
    float* q_W1T = ws + o;     o += HDIM * 64;
    int* iws = (int*)(ws + o);
    size_t io = 0;
    int* cnt = iws + io;     io += N_COL + N_CON;
    int* cursor = iws + io;  io += N_COL + N_CON;
    int* offs = iws + io;    io += N_COL + N_CON;
    int* partials = iws + io; io += 256;
    int* srclist = iws + io; io += 2 * (size_t)E;
    const int NTOT = N_COL + N_CON;

    prep_k<<<(109568 + 255) / 256, 256, 0, stream>>>(
        W_col, W_colT, W_con, W_conT,
        c1_cn_Wl, c1_cn_WlT, c1_cn_Wr, c1_cn_WrT,
        c1_nc_Wl, c1_nc_WlT, c1_nc_Wr, c1_nc_WrT,
        c2_nc_Wl, c2_nc_WlT, c2_nc_Wr, c2_nc_WrT,
        q_W1, q_W1T);

    encoder_k<16, __half><<<((size_t)N_COL * HDIM + 255) / 256, 256, 0, stream>>>(x_col, W_colT, b_col, h_colh, N_COL);
    encoder_k<8, float><<<((size_t)N_CON * HDIM + 255) / 256, 256, 0, stream>>>(x_con, W_conT, b_con, h_con, N_CON);

    // ---- unified CSR build ----
    hipMemsetAsync(cnt, 0, 2 * NTOT * sizeof(int), stream);
    count_k<<<(E + 255) / 256, 256, 0, stream>>>(edge_col, edge_con, cnt, E);
    int nb = (NTOT + SCAN_B - 1) / SCAN_B;
    scan1_k<<<nb, 256, 0, stream>>>(cnt, NTOT, offs, partials);
    scan2_k<<<1, 256, 0, stream>>>(partials, nb);
    scan3_k<<<(NTOT + 255) / 256, 256, 0, stream>>>(offs, NTOT, partials);
    fill2_k<<<(E + 255) / 256, 256, 0, stream>>>(edge_col, edge_con, offs, cursor, srclist, E);

    // ---- conv1 col->con (fp16 gather + dual GEMM) ----
    gather_mean_h_k<<<(N_CON + 3) / 4, 256, 0, stream>>>(h_colh, srclist, offs + N_COL, cnt + N_COL, buf1, N_CON);
    sage_gemm_k<<<(N_CON + 63) / 64, 256, 0, stream>>>(buf1, h_con, c1_cn_WlT, c1_cn_bl, c1_cn_WrT, n_con, N_CON);

    // ---- col gathered terms: combined lin (fp16 out) + one fp16 dual gather ----
    dim3 lgrid((N_CON + 63) / 64, 2);
    lin2_k<<<lgrid, 256, 0, stream>>>(h_con, c1_nc_WlT, n_con, c2_nc_WlT, linC, N_CON);
    gather_dual_k<<<(N_COL + 3) / 4, 256, 0, stream>>>(linC, srclist, offs, cnt, c0C, N_COL);

    // ---- fused encoder + conv1-nc + conv2-nc + Q-head ----
    col_mega_k<<<(N_COL + 63) / 64, 256, 0, stream>>>(c0C, x_col, W_colT, b_col,
                                                      c1_nc_WrT, c1_nc_bl, c2_nc_WrT, c2_nc_bl,
                                                      q_W1T, q_b1, q_W2, q_b2, out, N_COL);
}